// Round 10
// baseline (330.274 us; speedup 1.0000x reference)
//
#include <hip/hip_runtime.h>
#include <math.h>

#define LEN 17821
#define DMODEL 384
#define NHEAD 8
#define DHEAD 48
#define WSZ (384 * 384)

typedef float floatx4 __attribute__((ext_vector_type(4)));
typedef float floatx2 __attribute__((ext_vector_type(2)));
typedef short shortx8 __attribute__((ext_vector_type(8)));
typedef unsigned short ushort;

__device__ inline ushort f2bf(float f) {
    unsigned int u = __float_as_uint(f);
    u += 0x7FFFu + ((u >> 16) & 1u);
    return (ushort)(u >> 16);
}
__device__ inline float bf2f(ushort s) {
    return __uint_as_float(((unsigned int)s) << 16);
}

__device__ inline floatx4 mfma_bf16(shortx8 a, shortx8 b, floatx4 c) {
    return __builtin_amdgcn_mfma_f32_16x16x32_bf16(a, b, c, 0, 0, 0);
}

// ---------------------------------------------------------------------------
// Weight prep: 5 jobs -> [384,384] bf16, ALL packed in MFMA-fragment order
// for the 8-wave x 48-col GEMM shape:
//   idx = hs*12288 + wave*1536 + j*512 + lane*8 + e
//   -> W[wave*48 + j*16 + (lane&15)][hs*32 + (lane>>4)*8 + e]
// so every K-loop W load is a wave-coalesced 1KB segment.
// ---------------------------------------------------------------------------
__global__ __launch_bounds__(256)
void prep_w(const float* __restrict__ Wval, const float* __restrict__ Woff,
            const float* __restrict__ Wattn, const float* __restrict__ Wout,
            const float* __restrict__ w1xy, const float* __restrict__ w1zd,
            const float* __restrict__ w2xy, const float* __restrict__ w2zd,
            ushort* __restrict__ wv, ushort* __restrict__ woa,
            ushort* __restrict__ wo, ushort* __restrict__ w1b,
            ushort* __restrict__ w2b) {
    int idx = blockIdx.x * 256 + threadIdx.x;
    if (idx >= WSZ) return;
    int job = blockIdx.y;
    int e = idx & 7;
    int lane = (idx >> 3) & 63;
    int t = idx >> 9;            // 0..287
    int j = t % 3;
    int t2 = t / 3;              // 0..95
    int wv8 = t2 & 7;            // wave 0..7
    int hs = t2 >> 3;            // half-K-step 0..11
    int l15 = lane & 15, quad = lane >> 4;
    int row = wv8 * 48 + j * 16 + l15;   // output feature (W row)
    int k = hs * 32 + quad * 8 + e;      // reduction index
    float v; ushort* dst;
    if (job == 0) { v = Wval[row * 384 + k]; dst = wv; }
    else if (job == 1) {
        v = row < 256 ? Woff[row * 384 + k] : Wattn[(row - 256) * 384 + k];
        dst = woa;
    } else if (job == 2) { v = Wout[row * 384 + k]; dst = wo; }
    else if (job == 3) {
        v = row < 256 ? (k < 256 ? w1xy[row * 256 + k] : 0.f)
                      : (k >= 256 ? w1zd[(row - 256) * 128 + (k - 256)] : 0.f);
        dst = w1b;
    } else {
        v = row < 256 ? (k < 256 ? w2xy[row * 256 + k] : 0.f)
                      : (k >= 256 ? w2zd[(row - 256) * 128 + (k - 256)] : 0.f);
        dst = w2b;
    }
    dst[idx] = f2bf(v);
}

__global__ __launch_bounds__(384)
void prep_b(const float* __restrict__ boff, const float* __restrict__ battn,
            const float* __restrict__ b1xy, const float* __restrict__ b1zd,
            const float* __restrict__ b2xy, const float* __restrict__ b2zd,
            const float* __restrict__ g1xy, const float* __restrict__ be1xy,
            const float* __restrict__ g1zd, const float* __restrict__ be1zd,
            const float* __restrict__ g2xy, const float* __restrict__ be2xy,
            const float* __restrict__ g2zd, const float* __restrict__ be2zd,
            float* __restrict__ boa, float* __restrict__ b1c,
            float* __restrict__ b2c, float* __restrict__ l1g,
            float* __restrict__ l1b, float* __restrict__ l2g,
            float* __restrict__ l2b) {
    int i = threadIdx.x;
    bool lo = i < 256; int j = lo ? i : i - 256;
    boa[i] = lo ? boff[i] : battn[j];
    b1c[i] = lo ? b1xy[i] : b1zd[j];
    b2c[i] = lo ? b2xy[i] : b2zd[j];
    l1g[i] = lo ? g1xy[i] : g1zd[j];
    l1b[i] = lo ? be1xy[i] : be1zd[j];
    l2g[i] = lo ? g2xy[i] : g2zd[j];
    l2b[i] = lo ? be2xy[i] : be2zd[j];
}

// ---------------------------------------------------------------------------
// Shared GEMM tile shape (proven): MT=32 rows, 512 threads = 8 waves x
// 48-col strips, barrier-free half-K-step loop, depth-1 register prefetch
// of 3 packed-W fragments. A fragments from Cbuf (LDS).
// ---------------------------------------------------------------------------
#define MT 32
#define CST 392

#define GEMM384(WPTR)                                                         \
  {                                                                           \
    const ushort* wp_ = (WPTR) + wave * 1536 + lane * 8;                      \
    _Pragma("unroll")                                                         \
    for (int i_ = 0; i_ < 2; ++i_)                                            \
      _Pragma("unroll")                                                       \
      for (int j_ = 0; j_ < 3; ++j_) acc[i_][j_] = (floatx4){0.f,0.f,0.f,0.f};\
    shortx8 wcr[3], wnr[3];                                                   \
    _Pragma("unroll")                                                         \
    for (int j_ = 0; j_ < 3; ++j_)                                            \
      wcr[j_] = *(const shortx8*)(wp_ + j_ * 512);                            \
    _Pragma("unroll")                                                         \
    for (int hs = 0; hs < 12; ++hs) {                                         \
      if (hs < 11) {                                                          \
        _Pragma("unroll")                                                     \
        for (int j_ = 0; j_ < 3; ++j_)                                        \
          wnr[j_] = *(const shortx8*)(wp_ + (hs + 1) * 12288 + j_ * 512);     \
      }                                                                       \
      shortx8 a0 = *(shortx8*)&Cbuf[l15 * CST + hs * 32 + quad * 8];          \
      shortx8 a1 = *(shortx8*)&Cbuf[(16 + l15) * CST + hs * 32 + quad * 8];   \
      _Pragma("unroll")                                                       \
      for (int j_ = 0; j_ < 3; ++j_) {                                        \
        acc[0][j_] = mfma_bf16(a0, wcr[j_], acc[0][j_]);                      \
        acc[1][j_] = mfma_bf16(a1, wcr[j_], acc[1][j_]);                      \
      }                                                                       \
      if (hs < 11) {                                                          \
        _Pragma("unroll")                                                     \
        for (int j_ = 0; j_ < 3; ++j_) wcr[j_] = wnr[j_];                     \
      }                                                                       \
    }                                                                         \
  }

// ---------------------------------------------------------------------------
// vq_gemm v3 (round-10 proven): proven GEMM shape with cvt_add fused into
// staging. grid (557, 2): y=0 -> value = bf16(src) @ wv (bf16 out),
// y=1 -> offattn = bf16(src+pos) @ woa (fp32 out).
// ---------------------------------------------------------------------------
__global__ __launch_bounds__(512, 2)
void vq_gemm(const float* __restrict__ src, const float* __restrict__ pos,
             const ushort* __restrict__ wv, const ushort* __restrict__ woa,
             const float* __restrict__ bval, const float* __restrict__ boa,
             ushort* __restrict__ vout, float* __restrict__ oaout) {
    __shared__ __align__(16) ushort Cbuf[MT * CST];   // 25088 B
    bool job = blockIdx.y != 0;
    const ushort* Wp = job ? woa : wv;
    const float* bias = job ? boa : bval;
    int tid = threadIdx.x;
    int lane = tid & 63, wave = tid >> 6;
    int l15 = lane & 15, quad = lane >> 4;
    int wcol = wave * 48;
    int by0 = blockIdx.x * MT;

    // stage A: 32 rows x 384, fp32 -> bf16 (fused cvt_add), coalesced
    #pragma unroll
    for (int cix = 0; cix < 3; ++cix) {
        int idx = cix * 512 + tid;          // 0..1535
        int row = idx / 48, c = idx - row * 48;
        int gr = min(by0 + row, LEN - 1);
        const float* sp = src + (size_t)gr * 384 + c * 8;
        float4 a0 = *(const float4*)sp, a1 = *(const float4*)(sp + 4);
        if (job) {
            const float* pp = pos + (size_t)gr * 384 + c * 8;
            float4 p0 = *(const float4*)pp, p1 = *(const float4*)(pp + 4);
            a0.x += p0.x; a0.y += p0.y; a0.z += p0.z; a0.w += p0.w;
            a1.x += p1.x; a1.y += p1.y; a1.z += p1.z; a1.w += p1.w;
        }
        shortx8 b;
        b[0] = f2bf(a0.x); b[1] = f2bf(a0.y); b[2] = f2bf(a0.z); b[3] = f2bf(a0.w);
        b[4] = f2bf(a1.x); b[5] = f2bf(a1.y); b[6] = f2bf(a1.z); b[7] = f2bf(a1.w);
        *(shortx8*)(Cbuf + row * CST + c * 8) = b;
    }
    __syncthreads();

    floatx4 acc[2][3];
    GEMM384(Wp);

    #pragma unroll
    for (int j = 0; j < 3; ++j) {
        int col = wcol + j * 16 + l15;
        float bv = bias[col];
        #pragma unroll
        for (int i = 0; i < 2; ++i) {
            #pragma unroll
            for (int rr = 0; rr < 4; ++rr) {
                int gr = by0 + i * 16 + quad * 4 + rr;
                if (gr < LEN) {
                    float v = acc[i][j][rr] + bv;
                    if (job) oaout[(size_t)gr * 384 + col] = v;
                    else     vout[(size_t)gr * 384 + col] = f2bf(v);
                }
            }
        }
    }
}

// ---------------------------------------------------------------------------
// MEGA v11 (FUSED msda + out-proj + LN1 + FFN + LN2): the block gathers its
// own 32 tokens' MSDA output directly into Cbuf (4 sub-rounds of 8 tokens,
// msda_v4's proven softmax/table/gather phases), then runs the proven
// 3-stage GEMM. Eliminates the s3 27MB round-trip + one launch, and lets
// gather-phase (VALU-bound) blocks co-schedule with GEMM-phase (MFMA-bound)
// blocks on the same CU (m114 overlap). offattn and h1f alias (f0): each
// block reads offattn only for its own rows before writing h1 there, so no
// __restrict__ on those two args. LDS 70.7KB -> 2 blocks/CU = grid-limited
// residency anyway.
// ---------------------------------------------------------------------------
#define GTOK 8
__global__ __launch_bounds__(512, 2)
void mega_fused(const ushort* __restrict__ value,   // [LEN,384] bf16
                const float* offattn,               // [LEN,384] fp32 (=f0)
                const float* __restrict__ refpts,   // [LEN,4,2]
                const float* __restrict__ src,
                const ushort* __restrict__ Wo, const ushort* __restrict__ W1,
                const ushort* __restrict__ W2,
                const float* __restrict__ bo, const float* __restrict__ b1c,
                const float* __restrict__ b2c,
                const float* __restrict__ l1g, const float* __restrict__ l1b,
                const float* __restrict__ l2g, const float* __restrict__ l2b,
                float* h1f,                         // (=f0, aliases offattn)
                float* __restrict__ outp) {
    __shared__ __align__(16) ushort Cbuf[MT * CST];   // 25088 B
    __shared__ __align__(16) floatx4 pst4[MT * 16];   // 8192 B
    __shared__ __align__(16) floatx4 lnf[MT];         // 512 B
    __shared__ float saw[GTOK * 128];                 // 4096 B
    __shared__ int   si4[GTOK * 128][4];              // 16384 B
    __shared__ float sw4[GTOK * 128][4];              // 16384 B  (total 70656)

    constexpr int Wi[4]  = {134, 67, 34, 17};
    constexpr int Hi[4]  = {100, 50, 25, 13};
    constexpr int STi[4] = {0, 13400, 16750, 17600};

    int tid = threadIdx.x;
    int lane = tid & 63, wave = tid >> 6;          // wave 0..7
    int l15 = lane & 15, quad = lane >> 4;
    int wcol = wave * 48;
    int by0 = blockIdx.x * MT;

    // ================= MSDA gather: 4 sub-rounds of 8 tokens =================
    for (int r = 0; r < 4; ++r) {
        int tb = by0 + r * GTOK;
        // phase A: softmax -> saw (64 threads)
        if (tid < GTOK * 8) {
            int ti = tid >> 3, h = tid & 7, t = tb + ti;
            if (t < LEN) {
                const float* lg = offattn + (size_t)t * 384 + 256 + h * 16;
                float w[16], mx = -3.4e38f;
                #pragma unroll
                for (int s = 0; s < 16; ++s) { w[s] = lg[s]; mx = fmaxf(mx, w[s]); }
                float sum = 0.f;
                #pragma unroll
                for (int s = 0; s < 16; ++s) { w[s] = __expf(w[s] - mx); sum += w[s]; }
                float inv = 1.0f / sum;
                #pragma unroll
                for (int s = 0; s < 16; ++s) saw[ti * 128 + h * 16 + s] = w[s] * inv;
            }
        }
        __syncthreads();
        // phase B: fold coords+attn into 4 (weight,row) per (t,h,p)
        for (int idx = tid; idx < GTOK * 128; idx += 512) {
            int ti = idx >> 7, rem = idx & 127, h = rem >> 4, p = rem & 15;
            int lvl = p >> 2, pp = p & 3;
            int t = tb + ti;
            if (t < LEN) {
                float Wl = (float)Wi[lvl], Hl = (float)Hi[lvl];
                const int Wli = Wi[lvl], Hli = Hi[lvl], st = STi[lvl];
                const float* op = offattn + (size_t)t * 384 + h * 32 + lvl * 8 + pp * 2;
                float ox = op[0], oy = op[1];
                float rx = refpts[(size_t)t * 8 + lvl * 2];
                float ry = refpts[(size_t)t * 8 + lvl * 2 + 1];
                float x = rx * Wl + ox - 0.5f;
                float y = ry * Hl + oy - 0.5f;
                float x0f = floorf(x), y0f = floorf(y);
                int x0 = (int)x0f, y0 = (int)y0f;
                float dx = x - x0f, dy = y - y0f;
                float aw = saw[idx];
                float cwv[4] = {(1.f - dx) * (1.f - dy), dx * (1.f - dy),
                                (1.f - dx) * dy, dx * dy};
                #pragma unroll
                for (int c2 = 0; c2 < 4; ++c2) {
                    int xi = x0 + (c2 & 1), yi = y0 + (c2 >> 1);
                    bool valid = (xi >= 0) & (xi < Wli) & (yi >= 0) & (yi < Hli);
                    int xc = min(max(xi, 0), Wli - 1);
                    int yc = min(max(yi, 0), Hli - 1);
                    si4[idx][c2] = st + yc * Wli + xc;
                    sw4[idx][c2] = valid ? aw * cwv[c2] : 0.f;
                }
            }
        }
        __syncthreads();
        // phase C: gather -> Cbuf (384 threads: (ti,h,c))
        if (tid < GTOK * 48) {
            int ti = tid / 48;
            int rr2 = tid - ti * 48;
            int h = rr2 / 6;
            int c = rr2 - h * 6;
            int t = tb + ti;
            int row = r * GTOK + ti;
            shortx8 o = {};
            if (t < LEN) {
                const ushort* vb = value + h * DHEAD + c * 8;
                floatx2 a2[4] = {};
                #pragma unroll
                for (int p = 0; p < 16; ++p) {
                    int base = ti * 128 + h * 16 + p;
                    int4  I = *(const int4*)&si4[base][0];
                    float4 W4 = *(const float4*)&sw4[base][0];
                    const int   Iv[4] = {I.x, I.y, I.z, I.w};
                    const float Wv[4] = {W4.x, W4.y, W4.z, W4.w};
                    #pragma unroll
                    for (int c2 = 0; c2 < 4; ++c2) {
                        shortx8 g = *(const shortx8*)(vb + (size_t)Iv[c2] * 384);
                        float s = Wv[c2];
                        floatx2 s2 = {s, s};
                        const unsigned int* gu = (const unsigned int*)&g;
                        #pragma unroll
                        for (int q2 = 0; q2 < 4; ++q2) {
                            unsigned int u = gu[q2];
                            floatx2 gf;
                            gf[0] = __uint_as_float(u << 16);
                            gf[1] = __uint_as_float(u & 0xFFFF0000u);
                            a2[q2] += s2 * gf;
                        }
                    }
                }
                #pragma unroll
                for (int q2 = 0; q2 < 4; ++q2) {
                    o[q2 * 2]     = f2bf(a2[q2][0]);
                    o[q2 * 2 + 1] = f2bf(a2[q2][1]);
                }
            }
            *(shortx8*)(Cbuf + row * CST + h * DHEAD + c * 8) = o;
        }
        __syncthreads();
    }

    floatx4 acc[2][3];

    // ---------------- stage 1: src2 = msda @ Wo^T ----------------
    GEMM384(Wo);
    __syncthreads();                        // all waves done reading Cbuf

    // epilogue 1: x = src2 + b_out + src -> Cbuf (bf16)
    #pragma unroll
    for (int j = 0; j < 3; ++j) {
        int col = wcol + j * 16 + l15;
        float bv = bo[col];
        #pragma unroll
        for (int i = 0; i < 2; ++i)
            #pragma unroll
            for (int rr = 0; rr < 4; ++rr) {
                int row = i * 16 + quad * 4 + rr;
                int gr = min(by0 + row, LEN - 1);
                float x = acc[i][j][rr] + bv + src[(size_t)gr * 384 + col];
                Cbuf[row * CST + col] = f2bf(x);
            }
    }
    __syncthreads();

    // ---- LN1 ---- (512 threads: 16 partials/row, 24 cols each)
    {
        int row = tid >> 4, part = tid & 15;
        float sx = 0.f, qx = 0.f, sz = 0.f, qz = 0.f;
        #pragma unroll
        for (int m = 0; m < 3; ++m) {
            int c0 = part * 24 + m * 8;
            shortx8 v = *(shortx8*)(Cbuf + row * CST + c0);
            float cs = 0.f, cq = 0.f;
            #pragma unroll
            for (int e = 0; e < 8; ++e) { float x = bf2f(v[e]); cs += x; cq += x * x; }
            if (c0 < 256) { sx += cs; qx += cq; } else { sz += cs; qz += cq; }
        }
        pst4[row * 16 + part] = (floatx4){sx, qx, sz, qz};
    }
    __syncthreads();
    if (tid < MT) {
        floatx4 s = (floatx4){0.f, 0.f, 0.f, 0.f};
        #pragma unroll
        for (int p = 0; p < 16; ++p) s += pst4[tid * 16 + p];
        float mx = s[0] / 256.f, vx = s[1] / 256.f - mx * mx;
        float mz = s[2] / 128.f, vz = s[3] / 128.f - mz * mz;
        lnf[tid] = (floatx4){mx, rsqrtf(vx + 1e-5f), mz, rsqrtf(vz + 1e-5f)};
    }
    __syncthreads();
    {
        int row = tid >> 4, part = tid & 15;
        int gr = by0 + row;
        floatx4 L = lnf[row];
        #pragma unroll
        for (int m = 0; m < 3; ++m) {
            int c0 = part * 24 + m * 8;
            bool isxy = c0 < 256;
            float mean = isxy ? L[0] : L[2];
            float inv  = isxy ? L[1] : L[3];
            shortx8 v = *(shortx8*)(Cbuf + row * CST + c0);
            float4 g0 = *(const float4*)(l1g + c0), g1 = *(const float4*)(l1g + c0 + 4);
            float4 e0 = *(const float4*)(l1b + c0), e1 = *(const float4*)(l1b + c0 + 4);
            float gg[8] = {g0.x, g0.y, g0.z, g0.w, g1.x, g1.y, g1.z, g1.w};
            float ee[8] = {e0.x, e0.y, e0.z, e0.w, e1.x, e1.y, e1.z, e1.w};
            float h[8];
            shortx8 hb;
            #pragma unroll
            for (int e = 0; e < 8; ++e) {
                h[e] = (bf2f(v[e]) - mean) * inv * gg[e] + ee[e];
                hb[e] = f2bf(h[e]);
            }
            *(shortx8*)(Cbuf + row * CST + c0) = hb;
            if (gr < LEN) {
                *(float4*)(h1f + (size_t)gr * 384 + c0)     = make_float4(h[0], h[1], h[2], h[3]);
                *(float4*)(h1f + (size_t)gr * 384 + c0 + 4) = make_float4(h[4], h[5], h[6], h[7]);
            }
        }
    }
    __syncthreads();

    // ---------------- stage 2: hidden = relu(h1 @ W1^T + b1) ----------------
    GEMM384(W1);
    __syncthreads();                        // all waves done reading Cbuf
    #pragma unroll
    for (int j = 0; j < 3; ++j) {
        int col = wcol + j * 16 + l15;
        float bv = b1c[col];
        #pragma unroll
        for (int i = 0; i < 2; ++i)
            #pragma unroll
            for (int rr = 0; rr < 4; ++rr) {
                int row = i * 16 + quad * 4 + rr;
                Cbuf[row * CST + col] = f2bf(fmaxf(acc[i][j][rr] + bv, 0.f));
            }
    }
    __syncthreads();

    // ---------------- stage 3: x2 = hidden @ W2^T + b2 + h1 ----------------
    GEMM384(W2);
    __syncthreads();                        // all waves done reading Cbuf
    #pragma unroll
    for (int j = 0; j < 3; ++j) {
        int col = wcol + j * 16 + l15;
        float bv = b2c[col];
        #pragma unroll
        for (int i = 0; i < 2; ++i)
            #pragma unroll
            for (int rr = 0; rr < 4; ++rr) {
                int row = i * 16 + quad * 4 + rr;
                int gr = min(by0 + row, LEN - 1);
                float x = acc[i][j][rr] + bv + h1f[(size_t)gr * 384 + col];
                Cbuf[row * CST + col] = f2bf(x);
            }
    }
    __syncthreads();

    // ---- LN2 -> d_out ----
    {
        int row = tid >> 4, part = tid & 15;
        float sx = 0.f, qx = 0.f, sz = 0.f, qz = 0.f;
        #pragma unroll
        for (int m = 0; m < 3; ++m) {
            int c0 = part * 24 + m * 8;
            shortx8 v = *(shortx8*)(Cbuf + row * CST + c0);
            float cs = 0.f, cq = 0.f;
            #pragma unroll
            for (int e = 0; e < 8; ++e) { float x = bf2f(v[e]); cs += x; cq += x * x; }
            if (c0 < 256) { sx += cs; qx += cq; } else { sz += cs; qz += cq; }
        }
        pst4[row * 16 + part] = (floatx4){sx, qx, sz, qz};
    }
    __syncthreads();
    if (tid < MT) {
        floatx4 s = (floatx4){0.f, 0.f, 0.f, 0.f};
        #pragma unroll
        for (int p = 0; p < 16; ++p) s += pst4[tid * 16 + p];
        float mx = s[0] / 256.f, vx = s[1] / 256.f - mx * mx;
        float mz = s[2] / 128.f, vz = s[3] / 128.f - mz * mz;
        lnf[tid] = (floatx4){mx, rsqrtf(vx + 1e-5f), mz, rsqrtf(vz + 1e-5f)};
    }
    __syncthreads();
    {
        int row = tid >> 4, part = tid & 15;
        int gr = by0 + row;
        if (gr < LEN) {
            floatx4 L = lnf[row];
            #pragma unroll
            for (int m = 0; m < 3; ++m) {
                int c0 = part * 24 + m * 8;
                bool isxy = c0 < 256;
                float mean = isxy ? L[0] : L[2];
                float inv  = isxy ? L[1] : L[3];
                shortx8 v = *(shortx8*)(Cbuf + row * CST + c0);
                float4 g0 = *(const float4*)(l2g + c0), g1 = *(const float4*)(l2g + c0 + 4);
                float4 e0 = *(const float4*)(l2b + c0), e1 = *(const float4*)(l2b + c0 + 4);
                float gg[8] = {g0.x, g0.y, g0.z, g0.w, g1.x, g1.y, g1.z, g1.w};
                float ee[8] = {e0.x, e0.y, e0.z, e0.w, e1.x, e1.y, e1.z, e1.w};
                float h[8];
                #pragma unroll
                for (int e = 0; e < 8; ++e)
                    h[e] = (bf2f(v[e]) - mean) * inv * gg[e] + ee[e];
                *(float4*)(outp + (size_t)gr * 384 + c0)     = make_float4(h[0], h[1], h[2], h[3]);
                *(float4*)(outp + (size_t)gr * 384 + c0 + 4) = make_float4(h[4], h[5], h[6], h[7]);
            }
        }
    }
}

// ---------------------------------------------------------------------------
extern "C" void kernel_launch(void* const* d_in, const int* in_sizes, int n_in,
                              void* d_out, int out_size, void* d_ws, size_t ws_size,
                              hipStream_t stream) {
    const float* src    = (const float*)d_in[0];
    const float* pos    = (const float*)d_in[3];
    const float* refpts = (const float*)d_in[4];
    const float* W_off  = (const float*)d_in[8];
    const float* b_off  = (const float*)d_in[9];
    const float* W_attn = (const float*)d_in[10];
    const float* b_attn = (const float*)d_in[11];
    const float* W_val  = (const float*)d_in[12];
    const float* b_val  = (const float*)d_in[13];
    const float* W_out  = (const float*)d_in[14];
    const float* b_out  = (const float*)d_in[15];
    const float* g1xy = (const float*)d_in[16]; const float* b1xy = (const float*)d_in[17];
    const float* g1zd = (const float*)d_in[18]; const float* b1zd = (const float*)d_in[19];
    const float* fxy_w1 = (const float*)d_in[20]; const float* fxy_b1 = (const float*)d_in[21];
    const float* fxy_w2 = (const float*)d_in[22]; const float* fxy_b2 = (const float*)d_in[23];
    const float* fxy_g  = (const float*)d_in[24]; const float* fxy_b  = (const float*)d_in[25];
    const float* fzd_w1 = (const float*)d_in[26]; const float* fzd_b1 = (const float*)d_in[27];
    const float* fzd_w2 = (const float*)d_in[28]; const float* fzd_b2 = (const float*)d_in[29];
    const float* fzd_g  = (const float*)d_in[30]; const float* fzd_b  = (const float*)d_in[31];

    float* out = (float*)d_out;
    size_t Rn = (size_t)LEN * DMODEL;

    float* f0 = (float*)d_ws;                 // offattn fp32, later h1 fp32
    ushort* sb = (ushort*)(f0 + Rn);
    ushort* s2 = sb + 2 * Rn;                 // value_bf
    ushort* wv  = sb + 4 * Rn;
    ushort* woa = wv + WSZ;
    ushort* wo  = woa + WSZ;
    ushort* w1b = wo + WSZ;
    ushort* w2b = w1b + WSZ;
    float* bp = (float*)(w2b + WSZ);
    float* boa = bp;        float* b1c = bp + 384;  float* b2c = bp + 768;
    float* l1g = bp + 1152; float* l1b = bp + 1536;
    float* l2g = bp + 1920; float* l2b = bp + 2304;

    prep_w<<<dim3((WSZ + 255) / 256, 5), 256, 0, stream>>>(
        W_val, W_off, W_attn, W_out, fxy_w1, fzd_w1, fxy_w2, fzd_w2,
        wv, woa, wo, w1b, w2b);
    prep_b<<<1, 384, 0, stream>>>(b_off, b_attn, fxy_b1, fzd_b1, fxy_b2, fzd_b2,
                                  g1xy, b1xy, g1zd, b1zd, fxy_g, fxy_b, fzd_g, fzd_b,
                                  boa, b1c, b2c, l1g, l1b, l2g, l2b);

    vq_gemm<<<dim3((LEN + MT - 1) / MT, 2), 512, 0, stream>>>(
        src, pos, wv, woa, b_val, boa, s2, f0);

    mega_fused<<<(LEN + MT - 1) / MT, 512, 0, stream>>>(
        s2, f0, refpts, src, wo, w1b, w2b, b_out, b1c, b2c,
        l1g, l1b, l2g, l2b, f0, out);
}

// Round 11
// 298.321 us; speedup vs baseline: 1.1071x; 1.1071x over previous
//
#include <hip/hip_runtime.h>
#include <math.h>

#define LEN 17821
#define DMODEL 384
#define NHEAD 8
#define DHEAD 48
#define WSZ (384 * 384)

typedef float floatx4 __attribute__((ext_vector_type(4)));
typedef float floatx2 __attribute__((ext_vector_type(2)));
typedef short shortx8 __attribute__((ext_vector_type(8)));
typedef unsigned short ushort;

__device__ inline ushort f2bf(float f) {
    unsigned int u = __float_as_uint(f);
    u += 0x7FFFu + ((u >> 16) & 1u);
    return (ushort)(u >> 16);
}
__device__ inline float bf2f(ushort s) {
    return __uint_as_float(((unsigned int)s) << 16);
}

__device__ inline floatx4 mfma_bf16(shortx8 a, shortx8 b, floatx4 c) {
    return __builtin_amdgcn_mfma_f32_16x16x32_bf16(a, b, c, 0, 0, 0);
}

// ---------------------------------------------------------------------------
// Weight prep: 5 jobs -> [384,384] bf16, ALL packed in MFMA-fragment order
// for the 8-wave x 48-col GEMM shape:
//   idx = hs*12288 + wave*1536 + j*512 + lane*8 + e
//   -> W[wave*48 + j*16 + (lane&15)][hs*32 + (lane>>4)*8 + e]
// so every K-loop W load is a wave-coalesced 1KB segment.
// ---------------------------------------------------------------------------
__global__ __launch_bounds__(256)
void prep_w(const float* __restrict__ Wval, const float* __restrict__ Woff,
            const float* __restrict__ Wattn, const float* __restrict__ Wout,
            const float* __restrict__ w1xy, const float* __restrict__ w1zd,
            const float* __restrict__ w2xy, const float* __restrict__ w2zd,
            ushort* __restrict__ wv, ushort* __restrict__ woa,
            ushort* __restrict__ wo, ushort* __restrict__ w1b,
            ushort* __restrict__ w2b) {
    int idx = blockIdx.x * 256 + threadIdx.x;
    if (idx >= WSZ) return;
    int job = blockIdx.y;
    int e = idx & 7;
    int lane = (idx >> 3) & 63;
    int t = idx >> 9;            // 0..287
    int j = t % 3;
    int t2 = t / 3;              // 0..95
    int wv8 = t2 & 7;            // wave 0..7
    int hs = t2 >> 3;            // half-K-step 0..11
    int l15 = lane & 15, quad = lane >> 4;
    int row = wv8 * 48 + j * 16 + l15;   // output feature (W row)
    int k = hs * 32 + quad * 8 + e;      // reduction index
    float v; ushort* dst;
    if (job == 0) { v = Wval[row * 384 + k]; dst = wv; }
    else if (job == 1) {
        v = row < 256 ? Woff[row * 384 + k] : Wattn[(row - 256) * 384 + k];
        dst = woa;
    } else if (job == 2) { v = Wout[row * 384 + k]; dst = wo; }
    else if (job == 3) {
        v = row < 256 ? (k < 256 ? w1xy[row * 256 + k] : 0.f)
                      : (k >= 256 ? w1zd[(row - 256) * 128 + (k - 256)] : 0.f);
        dst = w1b;
    } else {
        v = row < 256 ? (k < 256 ? w2xy[row * 256 + k] : 0.f)
                      : (k >= 256 ? w2zd[(row - 256) * 128 + (k - 256)] : 0.f);
        dst = w2b;
    }
    dst[idx] = f2bf(v);
}

__global__ __launch_bounds__(384)
void prep_b(const float* __restrict__ boff, const float* __restrict__ battn,
            const float* __restrict__ b1xy, const float* __restrict__ b1zd,
            const float* __restrict__ b2xy, const float* __restrict__ b2zd,
            const float* __restrict__ g1xy, const float* __restrict__ be1xy,
            const float* __restrict__ g1zd, const float* __restrict__ be1zd,
            const float* __restrict__ g2xy, const float* __restrict__ be2xy,
            const float* __restrict__ g2zd, const float* __restrict__ be2zd,
            float* __restrict__ boa, float* __restrict__ b1c,
            float* __restrict__ b2c, float* __restrict__ l1g,
            float* __restrict__ l1b, float* __restrict__ l2g,
            float* __restrict__ l2b) {
    int i = threadIdx.x;
    bool lo = i < 256; int j = lo ? i : i - 256;
    boa[i] = lo ? boff[i] : battn[j];
    b1c[i] = lo ? b1xy[i] : b1zd[j];
    b2c[i] = lo ? b2xy[i] : b2zd[j];
    l1g[i] = lo ? g1xy[i] : g1zd[j];
    l1b[i] = lo ? be1xy[i] : be1zd[j];
    l2g[i] = lo ? g2xy[i] : g2zd[j];
    l2b[i] = lo ? be2xy[i] : be2zd[j];
}

// ---------------------------------------------------------------------------
// Shared GEMM tile shape: MT=32 rows, 512 threads = 8 waves x 48-col strips,
// barrier-free half-K-step loop. NOW depth-2 register prefetch (wcr/wnr/wn2
// rotation, 9 live fragments = 36 VGPR, under the 12-fragment bound v4
// proved stable) — covers ~2 half-steps of the ~200cy L2 latency instead
// of 1 (MfmaUtil was 9%: waves still stalled on W at depth-1).
// ---------------------------------------------------------------------------
#define MT 32
#define CST 392

#define GEMM384(WPTR)                                                         \
  {                                                                           \
    const ushort* wp_ = (WPTR) + wave * 1536 + lane * 8;                      \
    _Pragma("unroll")                                                         \
    for (int i_ = 0; i_ < 2; ++i_)                                            \
      _Pragma("unroll")                                                       \
      for (int j_ = 0; j_ < 3; ++j_) acc[i_][j_] = (floatx4){0.f,0.f,0.f,0.f};\
    shortx8 wcr[3], wnr[3], wn2[3];                                           \
    _Pragma("unroll")                                                         \
    for (int j_ = 0; j_ < 3; ++j_) {                                          \
      wcr[j_] = *(const shortx8*)(wp_ + j_ * 512);                            \
      wnr[j_] = *(const shortx8*)(wp_ + 12288 + j_ * 512);                    \
    }                                                                         \
    _Pragma("unroll")                                                         \
    for (int hs = 0; hs < 12; ++hs) {                                         \
      if (hs < 10) {                                                          \
        _Pragma("unroll")                                                     \
        for (int j_ = 0; j_ < 3; ++j_)                                        \
          wn2[j_] = *(const shortx8*)(wp_ + (hs + 2) * 12288 + j_ * 512);     \
      }                                                                       \
      shortx8 a0 = *(shortx8*)&Cbuf[l15 * CST + hs * 32 + quad * 8];          \
      shortx8 a1 = *(shortx8*)&Cbuf[(16 + l15) * CST + hs * 32 + quad * 8];   \
      _Pragma("unroll")                                                       \
      for (int j_ = 0; j_ < 3; ++j_) {                                        \
        acc[0][j_] = mfma_bf16(a0, wcr[j_], acc[0][j_]);                      \
        acc[1][j_] = mfma_bf16(a1, wcr[j_], acc[1][j_]);                      \
      }                                                                       \
      _Pragma("unroll")                                                       \
      for (int j_ = 0; j_ < 3; ++j_) wcr[j_] = wnr[j_];                       \
      if (hs < 10) {                                                          \
        _Pragma("unroll")                                                     \
        for (int j_ = 0; j_ < 3; ++j_) wnr[j_] = wn2[j_];                     \
      }                                                                       \
    }                                                                         \
  }

// ---------------------------------------------------------------------------
// vq_gemm v3 (round-10 proven): proven GEMM shape with cvt_add fused into
// staging. grid (557, 2): y=0 -> value = bf16(src) @ wv (bf16 out),
// y=1 -> offattn = bf16(src+pos) @ woa (fp32 out).
// ---------------------------------------------------------------------------
__global__ __launch_bounds__(512, 2)
void vq_gemm(const float* __restrict__ src, const float* __restrict__ pos,
             const ushort* __restrict__ wv, const ushort* __restrict__ woa,
             const float* __restrict__ bval, const float* __restrict__ boa,
             ushort* __restrict__ vout, float* __restrict__ oaout) {
    __shared__ __align__(16) ushort Cbuf[MT * CST];   // 25088 B
    bool job = blockIdx.y != 0;
    const ushort* Wp = job ? woa : wv;
    const float* bias = job ? boa : bval;
    int tid = threadIdx.x;
    int lane = tid & 63, wave = tid >> 6;
    int l15 = lane & 15, quad = lane >> 4;
    int wcol = wave * 48;
    int by0 = blockIdx.x * MT;

    // stage A: 32 rows x 384, fp32 -> bf16 (fused cvt_add), coalesced
    #pragma unroll
    for (int cix = 0; cix < 3; ++cix) {
        int idx = cix * 512 + tid;          // 0..1535
        int row = idx / 48, c = idx - row * 48;
        int gr = min(by0 + row, LEN - 1);
        const float* sp = src + (size_t)gr * 384 + c * 8;
        float4 a0 = *(const float4*)sp, a1 = *(const float4*)(sp + 4);
        if (job) {
            const float* pp = pos + (size_t)gr * 384 + c * 8;
            float4 p0 = *(const float4*)pp, p1 = *(const float4*)(pp + 4);
            a0.x += p0.x; a0.y += p0.y; a0.z += p0.z; a0.w += p0.w;
            a1.x += p1.x; a1.y += p1.y; a1.z += p1.z; a1.w += p1.w;
        }
        shortx8 b;
        b[0] = f2bf(a0.x); b[1] = f2bf(a0.y); b[2] = f2bf(a0.z); b[3] = f2bf(a0.w);
        b[4] = f2bf(a1.x); b[5] = f2bf(a1.y); b[6] = f2bf(a1.z); b[7] = f2bf(a1.w);
        *(shortx8*)(Cbuf + row * CST + c * 8) = b;
    }
    __syncthreads();

    floatx4 acc[2][3];
    GEMM384(Wp);

    #pragma unroll
    for (int j = 0; j < 3; ++j) {
        int col = wcol + j * 16 + l15;
        float bv = bias[col];
        #pragma unroll
        for (int i = 0; i < 2; ++i) {
            #pragma unroll
            for (int rr = 0; rr < 4; ++rr) {
                int gr = by0 + i * 16 + quad * 4 + rr;
                if (gr < LEN) {
                    float v = acc[i][j][rr] + bv;
                    if (job) oaout[(size_t)gr * 384 + col] = v;
                    else     vout[(size_t)gr * 384 + col] = f2bf(v);
                }
            }
        }
    }
}

// ---------------------------------------------------------------------------
// MSDA v5: v4 (corner table in LDS, packed floatx2 accumulation, bijective
// XCD swizzle) + BYTE offsets precomputed in the table (row*768 fits int32),
// removing the per-load 64-bit index multiply from the 53%-VALUBusy gather.
// ---------------------------------------------------------------------------
#define MTOK 8
#define NXCD 8
__global__ __launch_bounds__(384)
void msda_v5(const ushort* __restrict__ value,   // [LEN,384] bf16
             const float* __restrict__ offattn,  // [LEN,384] fp32
             const float* __restrict__ refpts,   // [LEN,4,2]
             ushort* __restrict__ out, int nwg) { // [LEN,384] bf16
    __shared__ float saw[MTOK * 128];             // 4 KB
    __shared__ int   si4[MTOK * 128][4];          // 16 KB  (BYTE offsets)
    __shared__ float sw4[MTOK * 128][4];          // 16 KB
    constexpr int Wi[4]  = {134, 67, 34, 17};
    constexpr int Hi[4]  = {100, 50, 25, 13};
    constexpr int STi[4] = {0, 13400, 16750, 17600};

    int orig = blockIdx.x;
    int q = nwg / NXCD, r = nwg % NXCD;
    int xcd = orig % NXCD, ci = orig / NXCD;
    int bid = (xcd < r ? xcd * (q + 1) : r * (q + 1) + (xcd - r) * q) + ci;
    int t0 = bid * MTOK;
    int tid = threadIdx.x;

    // phase A: softmax -> saw
    if (tid < MTOK * 8) {
        int ti = tid >> 3, h = tid & 7, t = t0 + ti;
        if (t < LEN) {
            const float* lg = offattn + (size_t)t * 384 + 256 + h * 16;
            float w[16], mx = -3.4e38f;
            #pragma unroll
            for (int s = 0; s < 16; ++s) { w[s] = lg[s]; mx = fmaxf(mx, w[s]); }
            float sum = 0.f;
            #pragma unroll
            for (int s = 0; s < 16; ++s) { w[s] = __expf(w[s] - mx); sum += w[s]; }
            float inv = 1.0f / sum;
            #pragma unroll
            for (int s = 0; s < 16; ++s) saw[ti * 128 + h * 16 + s] = w[s] * inv;
        }
    }
    __syncthreads();

    // phase B: fold coords + attention into 4 (weight, byte-offset) per entry
    for (int idx = tid; idx < MTOK * 128; idx += 384) {
        int ti = idx >> 7, rem = idx & 127, h = rem >> 4, p = rem & 15;
        int lvl = p >> 2, pp = p & 3;
        int t = t0 + ti;
        if (t < LEN) {
            float Wl = (float)Wi[lvl], Hl = (float)Hi[lvl];
            const int Wli = Wi[lvl], Hli = Hi[lvl], st = STi[lvl];
            const float* op = offattn + (size_t)t * 384 + h * 32 + lvl * 8 + pp * 2;
            float ox = op[0], oy = op[1];
            float rx = refpts[(size_t)t * 8 + lvl * 2];
            float ry = refpts[(size_t)t * 8 + lvl * 2 + 1];
            float x = rx * Wl + ox - 0.5f;
            float y = ry * Hl + oy - 0.5f;
            float x0f = floorf(x), y0f = floorf(y);
            int x0 = (int)x0f, y0 = (int)y0f;
            float dx = x - x0f, dy = y - y0f;
            float aw = saw[idx];
            float cwv[4] = {(1.f - dx) * (1.f - dy), dx * (1.f - dy),
                            (1.f - dx) * dy, dx * dy};
            #pragma unroll
            for (int c2 = 0; c2 < 4; ++c2) {
                int xi = x0 + (c2 & 1), yi = y0 + (c2 >> 1);
                bool valid = (xi >= 0) & (xi < Wli) & (yi >= 0) & (yi < Hli);
                int xc = min(max(xi, 0), Wli - 1);
                int yc = min(max(yi, 0), Hli - 1);
                si4[idx][c2] = (st + yc * Wli + xc) * 768;   // byte offset
                sw4[idx][c2] = valid ? aw * cwv[c2] : 0.f;
            }
        }
    }
    __syncthreads();

    // phase C: gather. thread = (ti, h, c): 8 contiguous elems of head h.
    int ti = tid / 48;
    int rr = tid - ti * 48;
    int h = rr / 6;
    int c = rr - h * 6;
    int t = t0 + ti;
    if (t >= LEN) return;
    const char* vbc = (const char*)value + (size_t)(h * DHEAD + c * 8) * 2;
    floatx2 a2[4] = {};
    #pragma unroll
    for (int p = 0; p < 16; ++p) {
        int base = ti * 128 + h * 16 + p;
        int4  I = *(const int4*)&si4[base][0];
        float4 W4 = *(const float4*)&sw4[base][0];
        const int   Iv[4] = {I.x, I.y, I.z, I.w};
        const float Wv[4] = {W4.x, W4.y, W4.z, W4.w};
        #pragma unroll
        for (int c2 = 0; c2 < 4; ++c2) {
            shortx8 g = *(const shortx8*)(vbc + Iv[c2]);
            float s = Wv[c2];
            floatx2 s2 = {s, s};
            const unsigned int* gu = (const unsigned int*)&g;
            #pragma unroll
            for (int q2 = 0; q2 < 4; ++q2) {
                unsigned int u = gu[q2];
                floatx2 gf;
                gf[0] = __uint_as_float(u << 16);
                gf[1] = __uint_as_float(u & 0xFFFF0000u);
                a2[q2] += s2 * gf;
            }
        }
    }
    shortx8 o;
    #pragma unroll
    for (int q2 = 0; q2 < 4; ++q2) {
        o[q2 * 2]     = f2bf(a2[q2][0]);
        o[q2 * 2 + 1] = f2bf(a2[q2][1]);
    }
    *(shortx8*)(out + (size_t)t * 384 + h * DHEAD + c * 8) = o;
}

// ---------------------------------------------------------------------------
// MEGA v8 structure (session-best serial form), GEMM384 now depth-2.
// ---------------------------------------------------------------------------
__global__ __launch_bounds__(512, 2)
void mega_kernel(const ushort* __restrict__ Amsda, const float* __restrict__ src,
                 const ushort* __restrict__ Wo, const ushort* __restrict__ W1,
                 const ushort* __restrict__ W2,
                 const float* __restrict__ bo, const float* __restrict__ b1c,
                 const float* __restrict__ b2c,
                 const float* __restrict__ l1g, const float* __restrict__ l1b,
                 const float* __restrict__ l2g, const float* __restrict__ l2b,
                 float* __restrict__ h1f, float* __restrict__ outp) {
    __shared__ __align__(16) ushort Cbuf[MT * CST];   // 25088 B
    __shared__ __align__(16) floatx4 pst4[MT * 16];   // 8192 B
    __shared__ __align__(16) floatx4 lnf[MT];         // 512 B (total 33792)

    int tid = threadIdx.x;
    int lane = tid & 63, wave = tid >> 6;          // wave 0..7
    int l15 = lane & 15, quad = lane >> 4;
    int wcol = wave * 48;
    int by0 = blockIdx.x * MT;

    floatx4 acc[2][3];

    // ---- stage A (msda output rows) into Cbuf once, coalesced ----
    #pragma unroll
    for (int cix = 0; cix < 3; ++cix) {
        int idx = cix * 512 + tid;          // 0..1535
        int row = idx / 48, c = idx - row * 48;
        int gr = min(by0 + row, LEN - 1);
        *(shortx8*)(Cbuf + row * CST + c * 8) =
            *(const shortx8*)(Amsda + (size_t)gr * 384 + c * 8);
    }
    __syncthreads();

    // ---------------- stage 1: src2 = msda @ Wo^T ----------------
    GEMM384(Wo);
    __syncthreads();                        // all waves done reading Cbuf

    // epilogue 1: x = src2 + b_out + src -> Cbuf (bf16)
    #pragma unroll
    for (int j = 0; j < 3; ++j) {
        int col = wcol + j * 16 + l15;
        float bv = bo[col];
        #pragma unroll
        for (int i = 0; i < 2; ++i)
            #pragma unroll
            for (int rr = 0; rr < 4; ++rr) {
                int row = i * 16 + quad * 4 + rr;
                int gr = min(by0 + row, LEN - 1);
                float x = acc[i][j][rr] + bv + src[(size_t)gr * 384 + col];
                Cbuf[row * CST + col] = f2bf(x);
            }
    }
    __syncthreads();

    // ---- LN1 ---- (512 threads: 16 partials/row, 24 cols each)
    {
        int row = tid >> 4, part = tid & 15;
        float sx = 0.f, qx = 0.f, sz = 0.f, qz = 0.f;
        #pragma unroll
        for (int m = 0; m < 3; ++m) {
            int c0 = part * 24 + m * 8;
            shortx8 v = *(shortx8*)(Cbuf + row * CST + c0);
            float cs = 0.f, cq = 0.f;
            #pragma unroll
            for (int e = 0; e < 8; ++e) { float x = bf2f(v[e]); cs += x; cq += x * x; }
            if (c0 < 256) { sx += cs; qx += cq; } else { sz += cs; qz += cq; }
        }
        pst4[row * 16 + part] = (floatx4){sx, qx, sz, qz};
    }
    __syncthreads();
    if (tid < MT) {
        floatx4 s = (floatx4){0.f, 0.f, 0.f, 0.f};
        #pragma unroll
        for (int p = 0; p < 16; ++p) s += pst4[tid * 16 + p];
        float mx = s[0] / 256.f, vx = s[1] / 256.f - mx * mx;
        float mz = s[2] / 128.f, vz = s[3] / 128.f - mz * mz;
        lnf[tid] = (floatx4){mx, rsqrtf(vx + 1e-5f), mz, rsqrtf(vz + 1e-5f)};
    }
    __syncthreads();
    {
        int row = tid >> 4, part = tid & 15;
        int gr = by0 + row;
        floatx4 L = lnf[row];
        #pragma unroll
        for (int m = 0; m < 3; ++m) {
            int c0 = part * 24 + m * 8;
            bool isxy = c0 < 256;
            float mean = isxy ? L[0] : L[2];
            float inv  = isxy ? L[1] : L[3];
            shortx8 v = *(shortx8*)(Cbuf + row * CST + c0);
            float4 g0 = *(const float4*)(l1g + c0), g1 = *(const float4*)(l1g + c0 + 4);
            float4 e0 = *(const float4*)(l1b + c0), e1 = *(const float4*)(l1b + c0 + 4);
            float gg[8] = {g0.x, g0.y, g0.z, g0.w, g1.x, g1.y, g1.z, g1.w};
            float ee[8] = {e0.x, e0.y, e0.z, e0.w, e1.x, e1.y, e1.z, e1.w};
            float h[8];
            shortx8 hb;
            #pragma unroll
            for (int e = 0; e < 8; ++e) {
                h[e] = (bf2f(v[e]) - mean) * inv * gg[e] + ee[e];
                hb[e] = f2bf(h[e]);
            }
            *(shortx8*)(Cbuf + row * CST + c0) = hb;
            if (gr < LEN) {
                *(float4*)(h1f + (size_t)gr * 384 + c0)     = make_float4(h[0], h[1], h[2], h[3]);
                *(float4*)(h1f + (size_t)gr * 384 + c0 + 4) = make_float4(h[4], h[5], h[6], h[7]);
            }
        }
    }
    __syncthreads();

    // ---------------- stage 2: hidden = relu(h1 @ W1^T + b1) ----------------
    GEMM384(W1);
    __syncthreads();                        // all waves done reading Cbuf
    #pragma unroll
    for (int j = 0; j < 3; ++j) {
        int col = wcol + j * 16 + l15;
        float bv = b1c[col];
        #pragma unroll
        for (int i = 0; i < 2; ++i)
            #pragma unroll
            for (int rr = 0; rr < 4; ++rr) {
                int row = i * 16 + quad * 4 + rr;
                Cbuf[row * CST + col] = f2bf(fmaxf(acc[i][j][rr] + bv, 0.f));
            }
    }
    __syncthreads();

    // ---------------- stage 3: x2 = hidden @ W2^T + b2 + h1 ----------------
    GEMM384(W2);
    __syncthreads();                        // all waves done reading Cbuf
    #pragma unroll
    for (int j = 0; j < 3; ++j) {
        int col = wcol + j * 16 + l15;
        float bv = b2c[col];
        #pragma unroll
        for (int i = 0; i < 2; ++i)
            #pragma unroll
            for (int rr = 0; rr < 4; ++rr) {
                int row = i * 16 + quad * 4 + rr;
                int gr = min(by0 + row, LEN - 1);
                float x = acc[i][j][rr] + bv + h1f[(size_t)gr * 384 + col];
                Cbuf[row * CST + col] = f2bf(x);
            }
    }
    __syncthreads();

    // ---- LN2 -> d_out ----
    {
        int row = tid >> 4, part = tid & 15;
        float sx = 0.f, qx = 0.f, sz = 0.f, qz = 0.f;
        #pragma unroll
        for (int m = 0; m < 3; ++m) {
            int c0 = part * 24 + m * 8;
            shortx8 v = *(shortx8*)(Cbuf + row * CST + c0);
            float cs = 0.f, cq = 0.f;
            #pragma unroll
            for (int e = 0; e < 8; ++e) { float x = bf2f(v[e]); cs += x; cq += x * x; }
            if (c0 < 256) { sx += cs; qx += cq; } else { sz += cs; qz += cq; }
        }
        pst4[row * 16 + part] = (floatx4){sx, qx, sz, qz};
    }
    __syncthreads();
    if (tid < MT) {
        floatx4 s = (floatx4){0.f, 0.f, 0.f, 0.f};
        #pragma unroll
        for (int p = 0; p < 16; ++p) s += pst4[tid * 16 + p];
        float mx = s[0] / 256.f, vx = s[1] / 256.f - mx * mx;
        float mz = s[2] / 128.f, vz = s[3] / 128.f - mz * mz;
        lnf[tid] = (floatx4){mx, rsqrtf(vx + 1e-5f), mz, rsqrtf(vz + 1e-5f)};
    }
    __syncthreads();
    {
        int row = tid >> 4, part = tid & 15;
        int gr = by0 + row;
        if (gr < LEN) {
            floatx4 L = lnf[row];
            #pragma unroll
            for (int m = 0; m < 3; ++m) {
                int c0 = part * 24 + m * 8;
                bool isxy = c0 < 256;
                float mean = isxy ? L[0] : L[2];
                float inv  = isxy ? L[1] : L[3];
                shortx8 v = *(shortx8*)(Cbuf + row * CST + c0);
                float4 g0 = *(const float4*)(l2g + c0), g1 = *(const float4*)(l2g + c0 + 4);
                float4 e0 = *(const float4*)(l2b + c0), e1 = *(const float4*)(l2b + c0 + 4);
                float gg[8] = {g0.x, g0.y, g0.z, g0.w, g1.x, g1.y, g1.z, g1.w};
                float ee[8] = {e0.x, e0.y, e0.z, e0.w, e1.x, e1.y, e1.z, e1.w};
                float h[8];
                #pragma unroll
                for (int e = 0; e < 8; ++e)
                    h[e] = (bf2f(v[e]) - mean) * inv * gg[e] + ee[e];
                *(float4*)(outp + (size_t)gr * 384 + c0)     = make_float4(h[0], h[1], h[2], h[3]);
                *(float4*)(outp + (size_t)gr * 384 + c0 + 4) = make_float4(h[4], h[5], h[6], h[7]);
            }
        }
    }
}

// ---------------------------------------------------------------------------
extern "C" void kernel_launch(void* const* d_in, const int* in_sizes, int n_in,
                              void* d_out, int out_size, void* d_ws, size_t ws_size,
                              hipStream_t stream) {
    const float* src    = (const float*)d_in[0];
    const float* pos    = (const float*)d_in[3];
    const float* refpts = (const float*)d_in[4];
    const float* W_off  = (const float*)d_in[8];
    const float* b_off  = (const float*)d_in[9];
    const float* W_attn = (const float*)d_in[10];
    const float* b_attn = (const float*)d_in[11];
    const float* W_val  = (const float*)d_in[12];
    const float* b_val  = (const float*)d_in[13];
    const float* W_out  = (const float*)d_in[14];
    const float* b_out  = (const float*)d_in[15];
    const float* g1xy = (const float*)d_in[16]; const float* b1xy = (const float*)d_in[17];
    const float* g1zd = (const float*)d_in[18]; const float* b1zd = (const float*)d_in[19];
    const float* fxy_w1 = (const float*)d_in[20]; const float* fxy_b1 = (const float*)d_in[21];
    const float* fxy_w2 = (const float*)d_in[22]; const float* fxy_b2 = (const float*)d_in[23];
    const float* fxy_g  = (const float*)d_in[24]; const float* fxy_b  = (const float*)d_in[25];
    const float* fzd_w1 = (const float*)d_in[26]; const float* fzd_b1 = (const float*)d_in[27];
    const float* fzd_w2 = (const float*)d_in[28]; const float* fzd_b2 = (const float*)d_in[29];
    const float* fzd_g  = (const float*)d_in[30]; const float* fzd_b  = (const float*)d_in[31];

    float* out = (float*)d_out;
    size_t Rn = (size_t)LEN * DMODEL;

    float* f0 = (float*)d_ws;                 // offattn fp32, later h1 fp32
    ushort* sb = (ushort*)(f0 + Rn);
    ushort* s2 = sb + 2 * Rn;                 // value_bf
    ushort* s3 = sb + 3 * Rn;                 // msda_bf
    ushort* wv  = sb + 4 * Rn;
    ushort* woa = wv + WSZ;
    ushort* wo  = woa + WSZ;
    ushort* w1b = wo + WSZ;
    ushort* w2b = w1b + WSZ;
    float* bp = (float*)(w2b + WSZ);
    float* boa = bp;        float* b1c = bp + 384;  float* b2c = bp + 768;
    float* l1g = bp + 1152; float* l1b = bp + 1536;
    float* l2g = bp + 1920; float* l2b = bp + 2304;

    prep_w<<<dim3((WSZ + 255) / 256, 5), 256, 0, stream>>>(
        W_val, W_off, W_attn, W_out, fxy_w1, fzd_w1, fxy_w2, fzd_w2,
        wv, woa, wo, w1b, w2b);
    prep_b<<<1, 384, 0, stream>>>(b_off, b_attn, fxy_b1, fzd_b1, fxy_b2, fzd_b2,
                                  g1xy, b1xy, g1zd, b1zd, fxy_g, fxy_b, fzd_g, fzd_b,
                                  boa, b1c, b2c, l1g, l1b, l2g, l2b);

    vq_gemm<<<dim3((LEN + MT - 1) / MT, 2), 512, 0, stream>>>(
        src, pos, wv, woa, b_val, boa, s2, f0);

    int nwg = (LEN + MTOK - 1) / MTOK;
    msda_v5<<<nwg, 384, 0, stream>>>(s2, f0, refpts, s3, nwg);

    mega_kernel<<<(LEN + MT - 1) / MT, 512, 0, stream>>>(
        s3, src, wo, w1b, w2b, b_out, b1c, b2c,
        l1g, l1b, l2g, l2b, f0, out);
}

// Round 12
// 297.183 us; speedup vs baseline: 1.1113x; 1.0038x over previous
//
#include <hip/hip_runtime.h>
#include <math.h>

#define LEN 17821
#define DMODEL 384
#define NHEAD 8
#define DHEAD 48
#define WSZ (384 * 384)

typedef float floatx4 __attribute__((ext_vector_type(4)));
typedef float floatx2 __attribute__((ext_vector_type(2)));
typedef short shortx8 __attribute__((ext_vector_type(8)));
typedef unsigned short ushort;

__device__ inline ushort f2bf(float f) {
    unsigned int u = __float_as_uint(f);
    u += 0x7FFFu + ((u >> 16) & 1u);
    return (ushort)(u >> 16);
}
__device__ inline float bf2f(ushort s) {
    return __uint_as_float(((unsigned int)s) << 16);
}

__device__ inline floatx4 mfma_bf16(shortx8 a, shortx8 b, floatx4 c) {
    return __builtin_amdgcn_mfma_f32_16x16x32_bf16(a, b, c, 0, 0, 0);
}

// ---------------------------------------------------------------------------
// Weight prep: 5 jobs -> [384,384] bf16, ALL packed in MFMA-fragment order
// for the 8-wave x 48-col GEMM shape:
//   idx = hs*12288 + wave*1536 + j*512 + lane*8 + e
//   -> W[wave*48 + j*16 + (lane&15)][hs*32 + (lane>>4)*8 + e]
// so every K-loop W load is a wave-coalesced 1KB segment.
// ---------------------------------------------------------------------------
__global__ __launch_bounds__(256)
void prep_w(const float* __restrict__ Wval, const float* __restrict__ Woff,
            const float* __restrict__ Wattn, const float* __restrict__ Wout,
            const float* __restrict__ w1xy, const float* __restrict__ w1zd,
            const float* __restrict__ w2xy, const float* __restrict__ w2zd,
            ushort* __restrict__ wv, ushort* __restrict__ woa,
            ushort* __restrict__ wo, ushort* __restrict__ w1b,
            ushort* __restrict__ w2b) {
    int idx = blockIdx.x * 256 + threadIdx.x;
    if (idx >= WSZ) return;
    int job = blockIdx.y;
    int e = idx & 7;
    int lane = (idx >> 3) & 63;
    int t = idx >> 9;            // 0..287
    int j = t % 3;
    int t2 = t / 3;              // 0..95
    int wv8 = t2 & 7;            // wave 0..7
    int hs = t2 >> 3;            // half-K-step 0..11
    int l15 = lane & 15, quad = lane >> 4;
    int row = wv8 * 48 + j * 16 + l15;   // output feature (W row)
    int k = hs * 32 + quad * 8 + e;      // reduction index
    float v; ushort* dst;
    if (job == 0) { v = Wval[row * 384 + k]; dst = wv; }
    else if (job == 1) {
        v = row < 256 ? Woff[row * 384 + k] : Wattn[(row - 256) * 384 + k];
        dst = woa;
    } else if (job == 2) { v = Wout[row * 384 + k]; dst = wo; }
    else if (job == 3) {
        v = row < 256 ? (k < 256 ? w1xy[row * 256 + k] : 0.f)
                      : (k >= 256 ? w1zd[(row - 256) * 128 + (k - 256)] : 0.f);
        dst = w1b;
    } else {
        v = row < 256 ? (k < 256 ? w2xy[row * 256 + k] : 0.f)
                      : (k >= 256 ? w2zd[(row - 256) * 128 + (k - 256)] : 0.f);
        dst = w2b;
    }
    dst[idx] = f2bf(v);
}

__global__ __launch_bounds__(384)
void prep_b(const float* __restrict__ boff, const float* __restrict__ battn,
            const float* __restrict__ b1xy, const float* __restrict__ b1zd,
            const float* __restrict__ b2xy, const float* __restrict__ b2zd,
            const float* __restrict__ g1xy, const float* __restrict__ be1xy,
            const float* __restrict__ g1zd, const float* __restrict__ be1zd,
            const float* __restrict__ g2xy, const float* __restrict__ be2xy,
            const float* __restrict__ g2zd, const float* __restrict__ be2zd,
            float* __restrict__ boa, float* __restrict__ b1c,
            float* __restrict__ b2c, float* __restrict__ l1g,
            float* __restrict__ l1b, float* __restrict__ l2g,
            float* __restrict__ l2b) {
    int i = threadIdx.x;
    bool lo = i < 256; int j = lo ? i : i - 256;
    boa[i] = lo ? boff[i] : battn[j];
    b1c[i] = lo ? b1xy[i] : b1zd[j];
    b2c[i] = lo ? b2xy[i] : b2zd[j];
    l1g[i] = lo ? g1xy[i] : g1zd[j];
    l1b[i] = lo ? be1xy[i] : be1zd[j];
    l2g[i] = lo ? g2xy[i] : g2zd[j];
    l2b[i] = lo ? be2xy[i] : be2zd[j];
}

// ---------------------------------------------------------------------------
// Shared GEMM tile shape (v10 proven, depth-1): MT=32 rows, 512 threads =
// 8 waves x 48-col strips, barrier-free half-K-step loop, depth-1 register
// prefetch of 3 packed-W fragments (the compiler's unique stable point —
// depth-2 and 6/12-fragment variants all get rematerialized and regress).
// ---------------------------------------------------------------------------
#define MT 32
#define CST 392

#define GEMM384(WPTR)                                                         \
  {                                                                           \
    const ushort* wp_ = (WPTR) + wave * 1536 + lane * 8;                      \
    _Pragma("unroll")                                                         \
    for (int i_ = 0; i_ < 2; ++i_)                                            \
      _Pragma("unroll")                                                       \
      for (int j_ = 0; j_ < 3; ++j_) acc[i_][j_] = (floatx4){0.f,0.f,0.f,0.f};\
    shortx8 wcr[3], wnr[3];                                                   \
    _Pragma("unroll")                                                         \
    for (int j_ = 0; j_ < 3; ++j_)                                            \
      wcr[j_] = *(const shortx8*)(wp_ + j_ * 512);                            \
    _Pragma("unroll")                                                         \
    for (int hs = 0; hs < 12; ++hs) {                                         \
      if (hs < 11) {                                                          \
        _Pragma("unroll")                                                     \
        for (int j_ = 0; j_ < 3; ++j_)                                        \
          wnr[j_] = *(const shortx8*)(wp_ + (hs + 1) * 12288 + j_ * 512);     \
      }                                                                       \
      shortx8 a0 = *(shortx8*)&Cbuf[l15 * CST + hs * 32 + quad * 8];          \
      shortx8 a1 = *(shortx8*)&Cbuf[(16 + l15) * CST + hs * 32 + quad * 8];   \
      _Pragma("unroll")                                                       \
      for (int j_ = 0; j_ < 3; ++j_) {                                        \
        acc[0][j_] = mfma_bf16(a0, wcr[j_], acc[0][j_]);                      \
        acc[1][j_] = mfma_bf16(a1, wcr[j_], acc[1][j_]);                      \
      }                                                                       \
      if (hs < 11) {                                                          \
        _Pragma("unroll")                                                     \
        for (int j_ = 0; j_ < 3; ++j_) wcr[j_] = wnr[j_];                     \
      }                                                                       \
    }                                                                         \
  }

// ---------------------------------------------------------------------------
// vq_gemm v3 (round-10 proven): proven GEMM shape with cvt_add fused into
// staging. grid (557, 2): y=0 -> value = bf16(src) @ wv (bf16 out),
// y=1 -> offattn = bf16(src+pos) @ woa (fp32 out).
// ---------------------------------------------------------------------------
__global__ __launch_bounds__(512, 2)
void vq_gemm(const float* __restrict__ src, const float* __restrict__ pos,
             const ushort* __restrict__ wv, const ushort* __restrict__ woa,
             const float* __restrict__ bval, const float* __restrict__ boa,
             ushort* __restrict__ vout, float* __restrict__ oaout) {
    __shared__ __align__(16) ushort Cbuf[MT * CST];   // 25088 B
    bool job = blockIdx.y != 0;
    const ushort* Wp = job ? woa : wv;
    const float* bias = job ? boa : bval;
    int tid = threadIdx.x;
    int lane = tid & 63, wave = tid >> 6;
    int l15 = lane & 15, quad = lane >> 4;
    int wcol = wave * 48;
    int by0 = blockIdx.x * MT;

    // stage A: 32 rows x 384, fp32 -> bf16 (fused cvt_add), coalesced
    #pragma unroll
    for (int cix = 0; cix < 3; ++cix) {
        int idx = cix * 512 + tid;          // 0..1535
        int row = idx / 48, c = idx - row * 48;
        int gr = min(by0 + row, LEN - 1);
        const float* sp = src + (size_t)gr * 384 + c * 8;
        float4 a0 = *(const float4*)sp, a1 = *(const float4*)(sp + 4);
        if (job) {
            const float* pp = pos + (size_t)gr * 384 + c * 8;
            float4 p0 = *(const float4*)pp, p1 = *(const float4*)(pp + 4);
            a0.x += p0.x; a0.y += p0.y; a0.z += p0.z; a0.w += p0.w;
            a1.x += p1.x; a1.y += p1.y; a1.z += p1.z; a1.w += p1.w;
        }
        shortx8 b;
        b[0] = f2bf(a0.x); b[1] = f2bf(a0.y); b[2] = f2bf(a0.z); b[3] = f2bf(a0.w);
        b[4] = f2bf(a1.x); b[5] = f2bf(a1.y); b[6] = f2bf(a1.z); b[7] = f2bf(a1.w);
        *(shortx8*)(Cbuf + row * CST + c * 8) = b;
    }
    __syncthreads();

    floatx4 acc[2][3];
    GEMM384(Wp);

    #pragma unroll
    for (int j = 0; j < 3; ++j) {
        int col = wcol + j * 16 + l15;
        float bv = bias[col];
        #pragma unroll
        for (int i = 0; i < 2; ++i) {
            #pragma unroll
            for (int rr = 0; rr < 4; ++rr) {
                int gr = by0 + i * 16 + quad * 4 + rr;
                if (gr < LEN) {
                    float v = acc[i][j][rr] + bv;
                    if (job) oaout[(size_t)gr * 384 + col] = v;
                    else     vout[(size_t)gr * 384 + col] = f2bf(v);
                }
            }
        }
    }
}

// ---------------------------------------------------------------------------
// MSDA v5 (round-12 proven): corner table in LDS with BYTE offsets
// (removes per-load 64-bit index mul from the 53%-VALUBusy gather),
// packed floatx2 accumulation, bijective XCD-chunked swizzle.
// ---------------------------------------------------------------------------
#define MTOK 8
#define NXCD 8
__global__ __launch_bounds__(384)
void msda_v5(const ushort* __restrict__ value,   // [LEN,384] bf16
             const float* __restrict__ offattn,  // [LEN,384] fp32
             const float* __restrict__ refpts,   // [LEN,4,2]
             ushort* __restrict__ out, int nwg) { // [LEN,384] bf16
    __shared__ float saw[MTOK * 128];             // 4 KB
    __shared__ int   si4[MTOK * 128][4];          // 16 KB  (BYTE offsets)
    __shared__ float sw4[MTOK * 128][4];          // 16 KB
    constexpr int Wi[4]  = {134, 67, 34, 17};
    constexpr int Hi[4]  = {100, 50, 25, 13};
    constexpr int STi[4] = {0, 13400, 16750, 17600};

    int orig = blockIdx.x;
    int q = nwg / NXCD, r = nwg % NXCD;
    int xcd = orig % NXCD, ci = orig / NXCD;
    int bid = (xcd < r ? xcd * (q + 1) : r * (q + 1) + (xcd - r) * q) + ci;
    int t0 = bid * MTOK;
    int tid = threadIdx.x;

    // phase A: softmax -> saw
    if (tid < MTOK * 8) {
        int ti = tid >> 3, h = tid & 7, t = t0 + ti;
        if (t < LEN) {
            const float* lg = offattn + (size_t)t * 384 + 256 + h * 16;
            float w[16], mx = -3.4e38f;
            #pragma unroll
            for (int s = 0; s < 16; ++s) { w[s] = lg[s]; mx = fmaxf(mx, w[s]); }
            float sum = 0.f;
            #pragma unroll
            for (int s = 0; s < 16; ++s) { w[s] = __expf(w[s] - mx); sum += w[s]; }
            float inv = 1.0f / sum;
            #pragma unroll
            for (int s = 0; s < 16; ++s) saw[ti * 128 + h * 16 + s] = w[s] * inv;
        }
    }
    __syncthreads();

    // phase B: fold coords + attention into 4 (weight, byte-offset) per entry
    for (int idx = tid; idx < MTOK * 128; idx += 384) {
        int ti = idx >> 7, rem = idx & 127, h = rem >> 4, p = rem & 15;
        int lvl = p >> 2, pp = p & 3;
        int t = t0 + ti;
        if (t < LEN) {
            float Wl = (float)Wi[lvl], Hl = (float)Hi[lvl];
            const int Wli = Wi[lvl], Hli = Hi[lvl], st = STi[lvl];
            const float* op = offattn + (size_t)t * 384 + h * 32 + lvl * 8 + pp * 2;
            float ox = op[0], oy = op[1];
            float rx = refpts[(size_t)t * 8 + lvl * 2];
            float ry = refpts[(size_t)t * 8 + lvl * 2 + 1];
            float x = rx * Wl + ox - 0.5f;
            float y = ry * Hl + oy - 0.5f;
            float x0f = floorf(x), y0f = floorf(y);
            int x0 = (int)x0f, y0 = (int)y0f;
            float dx = x - x0f, dy = y - y0f;
            float aw = saw[idx];
            float cwv[4] = {(1.f - dx) * (1.f - dy), dx * (1.f - dy),
                            (1.f - dx) * dy, dx * dy};
            #pragma unroll
            for (int c2 = 0; c2 < 4; ++c2) {
                int xi = x0 + (c2 & 1), yi = y0 + (c2 >> 1);
                bool valid = (xi >= 0) & (xi < Wli) & (yi >= 0) & (yi < Hli);
                int xc = min(max(xi, 0), Wli - 1);
                int yc = min(max(yi, 0), Hli - 1);
                si4[idx][c2] = (st + yc * Wli + xc) * 768;   // byte offset
                sw4[idx][c2] = valid ? aw * cwv[c2] : 0.f;
            }
        }
    }
    __syncthreads();

    // phase C: gather. thread = (ti, h, c): 8 contiguous elems of head h.
    int ti = tid / 48;
    int rr = tid - ti * 48;
    int h = rr / 6;
    int c = rr - h * 6;
    int t = t0 + ti;
    if (t >= LEN) return;
    const char* vbc = (const char*)value + (size_t)(h * DHEAD + c * 8) * 2;
    floatx2 a2[4] = {};
    #pragma unroll
    for (int p = 0; p < 16; ++p) {
        int base = ti * 128 + h * 16 + p;
        int4  I = *(const int4*)&si4[base][0];
        float4 W4 = *(const float4*)&sw4[base][0];
        const int   Iv[4] = {I.x, I.y, I.z, I.w};
        const float Wv[4] = {W4.x, W4.y, W4.z, W4.w};
        #pragma unroll
        for (int c2 = 0; c2 < 4; ++c2) {
            shortx8 g = *(const shortx8*)(vbc + Iv[c2]);
            float s = Wv[c2];
            floatx2 s2 = {s, s};
            const unsigned int* gu = (const unsigned int*)&g;
            #pragma unroll
            for (int q2 = 0; q2 < 4; ++q2) {
                unsigned int u = gu[q2];
                floatx2 gf;
                gf[0] = __uint_as_float(u << 16);
                gf[1] = __uint_as_float(u & 0xFFFF0000u);
                a2[q2] += s2 * gf;
            }
        }
    }
    shortx8 o;
    #pragma unroll
    for (int q2 = 0; q2 < 4; ++q2) {
        o[q2 * 2]     = f2bf(a2[q2][0]);
        o[q2 * 2 + 1] = f2bf(a2[q2][1]);
    }
    *(shortx8*)(out + (size_t)t * 384 + h * DHEAD + c * 8) = o;
}

// ---------------------------------------------------------------------------
// MEGA v8 (session-best): MT=32 rows, 557-block grid, 512 threads = 8 waves
// x 48-col strips, barrier-free half-K-step loop, depth-1 register prefetch
// (3 W fragments), h1 via global f0.
// ---------------------------------------------------------------------------
__global__ __launch_bounds__(512, 2)
void mega_kernel(const ushort* __restrict__ Amsda, const float* __restrict__ src,
                 const ushort* __restrict__ Wo, const ushort* __restrict__ W1,
                 const ushort* __restrict__ W2,
                 const float* __restrict__ bo, const float* __restrict__ b1c,
                 const float* __restrict__ b2c,
                 const float* __restrict__ l1g, const float* __restrict__ l1b,
                 const float* __restrict__ l2g, const float* __restrict__ l2b,
                 float* __restrict__ h1f, float* __restrict__ outp) {
    __shared__ __align__(16) ushort Cbuf[MT * CST];   // 25088 B
    __shared__ __align__(16) floatx4 pst4[MT * 16];   // 8192 B
    __shared__ __align__(16) floatx4 lnf[MT];         // 512 B (total 33792)

    int tid = threadIdx.x;
    int lane = tid & 63, wave = tid >> 6;          // wave 0..7
    int l15 = lane & 15, quad = lane >> 4;
    int wcol = wave * 48;
    int by0 = blockIdx.x * MT;

    floatx4 acc[2][3];

    // ---- stage A (msda output rows) into Cbuf once, coalesced ----
    #pragma unroll
    for (int cix = 0; cix < 3; ++cix) {
        int idx = cix * 512 + tid;          // 0..1535
        int row = idx / 48, c = idx - row * 48;
        int gr = min(by0 + row, LEN - 1);
        *(shortx8*)(Cbuf + row * CST + c * 8) =
            *(const shortx8*)(Amsda + (size_t)gr * 384 + c * 8);
    }
    __syncthreads();

    // ---------------- stage 1: src2 = msda @ Wo^T ----------------
    GEMM384(Wo);
    __syncthreads();                        // all waves done reading Cbuf

    // epilogue 1: x = src2 + b_out + src -> Cbuf (bf16)
    #pragma unroll
    for (int j = 0; j < 3; ++j) {
        int col = wcol + j * 16 + l15;
        float bv = bo[col];
        #pragma unroll
        for (int i = 0; i < 2; ++i)
            #pragma unroll
            for (int rr = 0; rr < 4; ++rr) {
                int row = i * 16 + quad * 4 + rr;
                int gr = min(by0 + row, LEN - 1);
                float x = acc[i][j][rr] + bv + src[(size_t)gr * 384 + col];
                Cbuf[row * CST + col] = f2bf(x);
            }
    }
    __syncthreads();

    // ---- LN1 ---- (512 threads: 16 partials/row, 24 cols each)
    {
        int row = tid >> 4, part = tid & 15;
        float sx = 0.f, qx = 0.f, sz = 0.f, qz = 0.f;
        #pragma unroll
        for (int m = 0; m < 3; ++m) {
            int c0 = part * 24 + m * 8;
            shortx8 v = *(shortx8*)(Cbuf + row * CST + c0);
            float cs = 0.f, cq = 0.f;
            #pragma unroll
            for (int e = 0; e < 8; ++e) { float x = bf2f(v[e]); cs += x; cq += x * x; }
            if (c0 < 256) { sx += cs; qx += cq; } else { sz += cs; qz += cq; }
        }
        pst4[row * 16 + part] = (floatx4){sx, qx, sz, qz};
    }
    __syncthreads();
    if (tid < MT) {
        floatx4 s = (floatx4){0.f, 0.f, 0.f, 0.f};
        #pragma unroll
        for (int p = 0; p < 16; ++p) s += pst4[tid * 16 + p];
        float mx = s[0] / 256.f, vx = s[1] / 256.f - mx * mx;
        float mz = s[2] / 128.f, vz = s[3] / 128.f - mz * mz;
        lnf[tid] = (floatx4){mx, rsqrtf(vx + 1e-5f), mz, rsqrtf(vz + 1e-5f)};
    }
    __syncthreads();
    {
        int row = tid >> 4, part = tid & 15;
        int gr = by0 + row;
        floatx4 L = lnf[row];
        #pragma unroll
        for (int m = 0; m < 3; ++m) {
            int c0 = part * 24 + m * 8;
            bool isxy = c0 < 256;
            float mean = isxy ? L[0] : L[2];
            float inv  = isxy ? L[1] : L[3];
            shortx8 v = *(shortx8*)(Cbuf + row * CST + c0);
            float4 g0 = *(const float4*)(l1g + c0), g1 = *(const float4*)(l1g + c0 + 4);
            float4 e0 = *(const float4*)(l1b + c0), e1 = *(const float4*)(l1b + c0 + 4);
            float gg[8] = {g0.x, g0.y, g0.z, g0.w, g1.x, g1.y, g1.z, g1.w};
            float ee[8] = {e0.x, e0.y, e0.z, e0.w, e1.x, e1.y, e1.z, e1.w};
            float h[8];
            shortx8 hb;
            #pragma unroll
            for (int e = 0; e < 8; ++e) {
                h[e] = (bf2f(v[e]) - mean) * inv * gg[e] + ee[e];
                hb[e] = f2bf(h[e]);
            }
            *(shortx8*)(Cbuf + row * CST + c0) = hb;
            if (gr < LEN) {
                *(float4*)(h1f + (size_t)gr * 384 + c0)     = make_float4(h[0], h[1], h[2], h[3]);
                *(float4*)(h1f + (size_t)gr * 384 + c0 + 4) = make_float4(h[4], h[5], h[6], h[7]);
            }
        }
    }
    __syncthreads();

    // ---------------- stage 2: hidden = relu(h1 @ W1^T + b1) ----------------
    GEMM384(W1);
    __syncthreads();                        // all waves done reading Cbuf
    #pragma unroll
    for (int j = 0; j < 3; ++j) {
        int col = wcol + j * 16 + l15;
        float bv = b1c[col];
        #pragma unroll
        for (int i = 0; i < 2; ++i)
            #pragma unroll
            for (int rr = 0; rr < 4; ++rr) {
                int row = i * 16 + quad * 4 + rr;
                Cbuf[row * CST + col] = f2bf(fmaxf(acc[i][j][rr] + bv, 0.f));
            }
    }
    __syncthreads();

    // ---------------- stage 3: x2 = hidden @ W2^T + b2 + h1 ----------------
    GEMM384(W2);
    __syncthreads();                        // all waves done reading Cbuf
    #pragma unroll
    for (int j = 0; j < 3; ++j) {
        int col = wcol + j * 16 + l15;
        float bv = b2c[col];
        #pragma unroll
        for (int i = 0; i < 2; ++i)
            #pragma unroll
            for (int rr = 0; rr < 4; ++rr) {
                int row = i * 16 + quad * 4 + rr;
                int gr = min(by0 + row, LEN - 1);
                float x = acc[i][j][rr] + bv + h1f[(size_t)gr * 384 + col];
                Cbuf[row * CST + col] = f2bf(x);
            }
    }
    __syncthreads();

    // ---- LN2 -> d_out ----
    {
        int row = tid >> 4, part = tid & 15;
        float sx = 0.f, qx = 0.f, sz = 0.f, qz = 0.f;
        #pragma unroll
        for (int m = 0; m < 3; ++m) {
            int c0 = part * 24 + m * 8;
            shortx8 v = *(shortx8*)(Cbuf + row * CST + c0);
            float cs = 0.f, cq = 0.f;
            #pragma unroll
            for (int e = 0; e < 8; ++e) { float x = bf2f(v[e]); cs += x; cq += x * x; }
            if (c0 < 256) { sx += cs; qx += cq; } else { sz += cs; qz += cq; }
        }
        pst4[row * 16 + part] = (floatx4){sx, qx, sz, qz};
    }
    __syncthreads();
    if (tid < MT) {
        floatx4 s = (floatx4){0.f, 0.f, 0.f, 0.f};
        #pragma unroll
        for (int p = 0; p < 16; ++p) s += pst4[tid * 16 + p];
        float mx = s[0] / 256.f, vx = s[1] / 256.f - mx * mx;
        float mz = s[2] / 128.f, vz = s[3] / 128.f - mz * mz;
        lnf[tid] = (floatx4){mx, rsqrtf(vx + 1e-5f), mz, rsqrtf(vz + 1e-5f)};
    }
    __syncthreads();
    {
        int row = tid >> 4, part = tid & 15;
        int gr = by0 + row;
        if (gr < LEN) {
            floatx4 L = lnf[row];
            #pragma unroll
            for (int m = 0; m < 3; ++m) {
                int c0 = part * 24 + m * 8;
                bool isxy = c0 < 256;
                float mean = isxy ? L[0] : L[2];
                float inv  = isxy ? L[1] : L[3];
                shortx8 v = *(shortx8*)(Cbuf + row * CST + c0);
                float4 g0 = *(const float4*)(l2g + c0), g1 = *(const float4*)(l2g + c0 + 4);
                float4 e0 = *(const float4*)(l2b + c0), e1 = *(const float4*)(l2b + c0 + 4);
                float gg[8] = {g0.x, g0.y, g0.z, g0.w, g1.x, g1.y, g1.z, g1.w};
                float ee[8] = {e0.x, e0.y, e0.z, e0.w, e1.x, e1.y, e1.z, e1.w};
                float h[8];
                #pragma unroll
                for (int e = 0; e < 8; ++e)
                    h[e] = (bf2f(v[e]) - mean) * inv * gg[e] + ee[e];
                *(float4*)(outp + (size_t)gr * 384 + c0)     = make_float4(h[0], h[1], h[2], h[3]);
                *(float4*)(outp + (size_t)gr * 384 + c0 + 4) = make_float4(h[4], h[5], h[6], h[7]);
            }
        }
    }
}

// ---------------------------------------------------------------------------
extern "C" void kernel_launch(void* const* d_in, const int* in_sizes, int n_in,
                              void* d_out, int out_size, void* d_ws, size_t ws_size,
                              hipStream_t stream) {
    const float* src    = (const float*)d_in[0];
    const float* pos    = (const float*)d_in[3];
    const float* refpts = (const float*)d_in[4];
    const float* W_off  = (const float*)d_in[8];
    const float* b_off  = (const float*)d_in[9];
    const float* W_attn = (const float*)d_in[10];
    const float* b_attn = (const float*)d_in[11];
    const float* W_val  = (const float*)d_in[12];
    const float* b_val  = (const float*)d_in[13];
    const float* W_out  = (const float*)d_in[14];
    const float* b_out  = (const float*)d_in[15];
    const float* g1xy = (const float*)d_in[16]; const float* b1xy = (const float*)d_in[17];
    const float* g1zd = (const float*)d_in[18]; const float* b1zd = (const float*)d_in[19];
    const float* fxy_w1 = (const float*)d_in[20]; const float* fxy_b1 = (const float*)d_in[21];
    const float* fxy_w2 = (const float*)d_in[22]; const float* fxy_b2 = (const float*)d_in[23];
    const float* fxy_g  = (const float*)d_in[24]; const float* fxy_b  = (const float*)d_in[25];
    const float* fzd_w1 = (const float*)d_in[26]; const float* fzd_b1 = (const float*)d_in[27];
    const float* fzd_w2 = (const float*)d_in[28]; const float* fzd_b2 = (const float*)d_in[29];
    const float* fzd_g  = (const float*)d_in[30]; const float* fzd_b  = (const float*)d_in[31];

    float* out = (float*)d_out;
    size_t Rn = (size_t)LEN * DMODEL;

    float* f0 = (float*)d_ws;                 // offattn fp32, later h1 fp32
    ushort* sb = (ushort*)(f0 + Rn);
    ushort* s2 = sb + 2 * Rn;                 // value_bf
    ushort* s3 = sb + 3 * Rn;                 // msda_bf
    ushort* wv  = sb + 4 * Rn;
    ushort* woa = wv + WSZ;
    ushort* wo  = woa + WSZ;
    ushort* w1b = wo + WSZ;
    ushort* w2b = w1b + WSZ;
    float* bp = (float*)(w2b + WSZ);
    float* boa = bp;        float* b1c = bp + 384;  float* b2c = bp + 768;
    float* l1g = bp + 1152; float* l1b = bp + 1536;
    float* l2g = bp + 1920; float* l2b = bp + 2304;

    prep_w<<<dim3((WSZ + 255) / 256, 5), 256, 0, stream>>>(
        W_val, W_off, W_attn, W_out, fxy_w1, fzd_w1, fxy_w2, fzd_w2,
        wv, woa, wo, w1b, w2b);
    prep_b<<<1, 384, 0, stream>>>(b_off, b_attn, fxy_b1, fzd_b1, fxy_b2, fzd_b2,
                                  g1xy, b1xy, g1zd, b1zd, fxy_g, fxy_b, fzd_g, fzd_b,
                                  boa, b1c, b2c, l1g, l1b, l2g, l2b);

    vq_gemm<<<dim3((LEN + MT - 1) / MT, 2), 512, 0, stream>>>(
        src, pos, wv, woa, b_val, boa, s2, f0);

    int nwg = (LEN + MTOK - 1) / MTOK;
    msda_v5<<<nwg, 384, 0, stream>>>(s2, f0, refpts, s3, nwg);

    mega_kernel<<<(LEN + MT - 1) / MT, 512, 0, stream>>>(
        s3, src, wo, w1b, w2b, b_out, b1c, b2c,
        l1g, l1b, l2g, l2b, f0, out);
}

// Round 13
// 293.158 us; speedup vs baseline: 1.1266x; 1.0137x over previous
//
#include <hip/hip_runtime.h>
#include <math.h>

#define LEN 17821
#define DMODEL 384
#define NHEAD 8
#define DHEAD 48
#define WSZ (384 * 384)

typedef float floatx4 __attribute__((ext_vector_type(4)));
typedef float floatx2 __attribute__((ext_vector_type(2)));
typedef short shortx8 __attribute__((ext_vector_type(8)));
typedef unsigned short ushort;

__device__ inline ushort f2bf(float f) {
    unsigned int u = __float_as_uint(f);
    u += 0x7FFFu + ((u >> 16) & 1u);
    return (ushort)(u >> 16);
}
__device__ inline float bf2f(ushort s) {
    return __uint_as_float(((unsigned int)s) << 16);
}

__device__ inline floatx4 mfma_bf16(shortx8 a, shortx8 b, floatx4 c) {
    return __builtin_amdgcn_mfma_f32_16x16x32_bf16(a, b, c, 0, 0, 0);
}

// ---------------------------------------------------------------------------
// Weight prep: 5 jobs -> [384,384] bf16, ALL packed in MFMA-fragment order
// for the 8-wave x 48-col GEMM shape:
//   idx = hs*12288 + wave*1536 + j*512 + lane*8 + e
//   -> W[wave*48 + j*16 + (lane&15)][hs*32 + (lane>>4)*8 + e]
// so every K-loop W load is a wave-coalesced 1KB segment.
// ---------------------------------------------------------------------------
__global__ __launch_bounds__(256)
void prep_w(const float* __restrict__ Wval, const float* __restrict__ Woff,
            const float* __restrict__ Wattn, const float* __restrict__ Wout,
            const float* __restrict__ w1xy, const float* __restrict__ w1zd,
            const float* __restrict__ w2xy, const float* __restrict__ w2zd,
            ushort* __restrict__ wv, ushort* __restrict__ woa,
            ushort* __restrict__ wo, ushort* __restrict__ w1b,
            ushort* __restrict__ w2b) {
    int idx = blockIdx.x * 256 + threadIdx.x;
    if (idx >= WSZ) return;
    int job = blockIdx.y;
    int e = idx & 7;
    int lane = (idx >> 3) & 63;
    int t = idx >> 9;            // 0..287
    int j = t % 3;
    int t2 = t / 3;              // 0..95
    int wv8 = t2 & 7;            // wave 0..7
    int hs = t2 >> 3;            // half-K-step 0..11
    int l15 = lane & 15, quad = lane >> 4;
    int row = wv8 * 48 + j * 16 + l15;   // output feature (W row)
    int k = hs * 32 + quad * 8 + e;      // reduction index
    float v; ushort* dst;
    if (job == 0) { v = Wval[row * 384 + k]; dst = wv; }
    else if (job == 1) {
        v = row < 256 ? Woff[row * 384 + k] : Wattn[(row - 256) * 384 + k];
        dst = woa;
    } else if (job == 2) { v = Wout[row * 384 + k]; dst = wo; }
    else if (job == 3) {
        v = row < 256 ? (k < 256 ? w1xy[row * 256 + k] : 0.f)
                      : (k >= 256 ? w1zd[(row - 256) * 128 + (k - 256)] : 0.f);
        dst = w1b;
    } else {
        v = row < 256 ? (k < 256 ? w2xy[row * 256 + k] : 0.f)
                      : (k >= 256 ? w2zd[(row - 256) * 128 + (k - 256)] : 0.f);
        dst = w2b;
    }
    dst[idx] = f2bf(v);
}

__global__ __launch_bounds__(384)
void prep_b(const float* __restrict__ boff, const float* __restrict__ battn,
            const float* __restrict__ b1xy, const float* __restrict__ b1zd,
            const float* __restrict__ b2xy, const float* __restrict__ b2zd,
            const float* __restrict__ g1xy, const float* __restrict__ be1xy,
            const float* __restrict__ g1zd, const float* __restrict__ be1zd,
            const float* __restrict__ g2xy, const float* __restrict__ be2xy,
            const float* __restrict__ g2zd, const float* __restrict__ be2zd,
            float* __restrict__ boa, float* __restrict__ b1c,
            float* __restrict__ b2c, float* __restrict__ l1g,
            float* __restrict__ l1b, float* __restrict__ l2g,
            float* __restrict__ l2b) {
    int i = threadIdx.x;
    bool lo = i < 256; int j = lo ? i : i - 256;
    boa[i] = lo ? boff[i] : battn[j];
    b1c[i] = lo ? b1xy[i] : b1zd[j];
    b2c[i] = lo ? b2xy[i] : b2zd[j];
    l1g[i] = lo ? g1xy[i] : g1zd[j];
    l1b[i] = lo ? be1xy[i] : be1zd[j];
    l2g[i] = lo ? g2xy[i] : g2zd[j];
    l2b[i] = lo ? be2xy[i] : be2zd[j];
}

// ---------------------------------------------------------------------------
// Shared GEMM tile shape: MT=32 rows, 512 threads = 8 waves x 48-col strips,
// barrier-free half-K-step loop.
// Two variants, each proven IN ITS HOST KERNEL:
//  - GEMM384   (depth-1, 6 live fragments): the only form the compiler keeps
//    inside mega's 3-instantiation + LN register environment (v8/v13: 66us;
//    depth-2 there collapses to copies and costs +12us, v12).
//  - GEMM384D2 (depth-2, 9 live fragments): kept intact in vq_gemm's single
//    instantiation, worth ~10us there (v12 ledger: rest 230.8 -> 221.1).
// ---------------------------------------------------------------------------
#define MT 32
#define CST 392

#define GEMM384(WPTR)                                                         \
  {                                                                           \
    const ushort* wp_ = (WPTR) + wave * 1536 + lane * 8;                      \
    _Pragma("unroll")                                                         \
    for (int i_ = 0; i_ < 2; ++i_)                                            \
      _Pragma("unroll")                                                       \
      for (int j_ = 0; j_ < 3; ++j_) acc[i_][j_] = (floatx4){0.f,0.f,0.f,0.f};\
    shortx8 wcr[3], wnr[3];                                                   \
    _Pragma("unroll")                                                         \
    for (int j_ = 0; j_ < 3; ++j_)                                            \
      wcr[j_] = *(const shortx8*)(wp_ + j_ * 512);                            \
    _Pragma("unroll")                                                         \
    for (int hs = 0; hs < 12; ++hs) {                                         \
      if (hs < 11) {                                                          \
        _Pragma("unroll")                                                     \
        for (int j_ = 0; j_ < 3; ++j_)                                        \
          wnr[j_] = *(const shortx8*)(wp_ + (hs + 1) * 12288 + j_ * 512);     \
      }                                                                       \
      shortx8 a0 = *(shortx8*)&Cbuf[l15 * CST + hs * 32 + quad * 8];          \
      shortx8 a1 = *(shortx8*)&Cbuf[(16 + l15) * CST + hs * 32 + quad * 8];   \
      _Pragma("unroll")                                                       \
      for (int j_ = 0; j_ < 3; ++j_) {                                        \
        acc[0][j_] = mfma_bf16(a0, wcr[j_], acc[0][j_]);                      \
        acc[1][j_] = mfma_bf16(a1, wcr[j_], acc[1][j_]);                      \
      }                                                                       \
      if (hs < 11) {                                                          \
        _Pragma("unroll")                                                     \
        for (int j_ = 0; j_ < 3; ++j_) wcr[j_] = wnr[j_];                     \
      }                                                                       \
    }                                                                         \
  }

#define GEMM384D2(WPTR)                                                       \
  {                                                                           \
    const ushort* wp_ = (WPTR) + wave * 1536 + lane * 8;                      \
    _Pragma("unroll")                                                         \
    for (int i_ = 0; i_ < 2; ++i_)                                            \
      _Pragma("unroll")                                                       \
      for (int j_ = 0; j_ < 3; ++j_) acc[i_][j_] = (floatx4){0.f,0.f,0.f,0.f};\
    shortx8 wcr[3], wnr[3], wn2[3];                                           \
    _Pragma("unroll")                                                         \
    for (int j_ = 0; j_ < 3; ++j_) {                                          \
      wcr[j_] = *(const shortx8*)(wp_ + j_ * 512);                            \
      wnr[j_] = *(const shortx8*)(wp_ + 12288 + j_ * 512);                    \
    }                                                                         \
    _Pragma("unroll")                                                         \
    for (int hs = 0; hs < 12; ++hs) {                                         \
      if (hs < 10) {                                                          \
        _Pragma("unroll")                                                     \
        for (int j_ = 0; j_ < 3; ++j_)                                        \
          wn2[j_] = *(const shortx8*)(wp_ + (hs + 2) * 12288 + j_ * 512);     \
      }                                                                       \
      shortx8 a0 = *(shortx8*)&Cbuf[l15 * CST + hs * 32 + quad * 8];          \
      shortx8 a1 = *(shortx8*)&Cbuf[(16 + l15) * CST + hs * 32 + quad * 8];   \
      _Pragma("unroll")                                                       \
      for (int j_ = 0; j_ < 3; ++j_) {                                        \
        acc[0][j_] = mfma_bf16(a0, wcr[j_], acc[0][j_]);                      \
        acc[1][j_] = mfma_bf16(a1, wcr[j_], acc[1][j_]);                      \
      }                                                                       \
      _Pragma("unroll")                                                       \
      for (int j_ = 0; j_ < 3; ++j_) wcr[j_] = wnr[j_];                       \
      if (hs < 10) {                                                          \
        _Pragma("unroll")                                                     \
        for (int j_ = 0; j_ < 3; ++j_) wnr[j_] = wn2[j_];                     \
      }                                                                       \
    }                                                                         \
  }

// ---------------------------------------------------------------------------
// vq_gemm (depth-2 GEMM, cvt_add fused into staging). grid (557, 2):
// y=0 -> value = bf16(src) @ wv (bf16 out),
// y=1 -> offattn = bf16(src+pos) @ woa (fp32 out).
// ---------------------------------------------------------------------------
__global__ __launch_bounds__(512, 2)
void vq_gemm(const float* __restrict__ src, const float* __restrict__ pos,
             const ushort* __restrict__ wv, const ushort* __restrict__ woa,
             const float* __restrict__ bval, const float* __restrict__ boa,
             ushort* __restrict__ vout, float* __restrict__ oaout) {
    __shared__ __align__(16) ushort Cbuf[MT * CST];   // 25088 B
    bool job = blockIdx.y != 0;
    const ushort* Wp = job ? woa : wv;
    const float* bias = job ? boa : bval;
    int tid = threadIdx.x;
    int lane = tid & 63, wave = tid >> 6;
    int l15 = lane & 15, quad = lane >> 4;
    int wcol = wave * 48;
    int by0 = blockIdx.x * MT;

    // stage A: 32 rows x 384, fp32 -> bf16 (fused cvt_add), coalesced
    #pragma unroll
    for (int cix = 0; cix < 3; ++cix) {
        int idx = cix * 512 + tid;          // 0..1535
        int row = idx / 48, c = idx - row * 48;
        int gr = min(by0 + row, LEN - 1);
        const float* sp = src + (size_t)gr * 384 + c * 8;
        float4 a0 = *(const float4*)sp, a1 = *(const float4*)(sp + 4);
        if (job) {
            const float* pp = pos + (size_t)gr * 384 + c * 8;
            float4 p0 = *(const float4*)pp, p1 = *(const float4*)(pp + 4);
            a0.x += p0.x; a0.y += p0.y; a0.z += p0.z; a0.w += p0.w;
            a1.x += p1.x; a1.y += p1.y; a1.z += p1.z; a1.w += p1.w;
        }
        shortx8 b;
        b[0] = f2bf(a0.x); b[1] = f2bf(a0.y); b[2] = f2bf(a0.z); b[3] = f2bf(a0.w);
        b[4] = f2bf(a1.x); b[5] = f2bf(a1.y); b[6] = f2bf(a1.z); b[7] = f2bf(a1.w);
        *(shortx8*)(Cbuf + row * CST + c * 8) = b;
    }
    __syncthreads();

    floatx4 acc[2][3];
    GEMM384D2(Wp);

    #pragma unroll
    for (int j = 0; j < 3; ++j) {
        int col = wcol + j * 16 + l15;
        float bv = bias[col];
        #pragma unroll
        for (int i = 0; i < 2; ++i) {
            #pragma unroll
            for (int rr = 0; rr < 4; ++rr) {
                int gr = by0 + i * 16 + quad * 4 + rr;
                if (gr < LEN) {
                    float v = acc[i][j][rr] + bv;
                    if (job) oaout[(size_t)gr * 384 + col] = v;
                    else     vout[(size_t)gr * 384 + col] = f2bf(v);
                }
            }
        }
    }
}

// ---------------------------------------------------------------------------
// MSDA v5: corner table in LDS with BYTE offsets, packed floatx2
// accumulation, bijective XCD-chunked swizzle.
// ---------------------------------------------------------------------------
#define MTOK 8
#define NXCD 8
__global__ __launch_bounds__(384)
void msda_v5(const ushort* __restrict__ value,   // [LEN,384] bf16
             const float* __restrict__ offattn,  // [LEN,384] fp32
             const float* __restrict__ refpts,   // [LEN,4,2]
             ushort* __restrict__ out, int nwg) { // [LEN,384] bf16
    __shared__ float saw[MTOK * 128];             // 4 KB
    __shared__ int   si4[MTOK * 128][4];          // 16 KB  (BYTE offsets)
    __shared__ float sw4[MTOK * 128][4];          // 16 KB
    constexpr int Wi[4]  = {134, 67, 34, 17};
    constexpr int Hi[4]  = {100, 50, 25, 13};
    constexpr int STi[4] = {0, 13400, 16750, 17600};

    int orig = blockIdx.x;
    int q = nwg / NXCD, r = nwg % NXCD;
    int xcd = orig % NXCD, ci = orig / NXCD;
    int bid = (xcd < r ? xcd * (q + 1) : r * (q + 1) + (xcd - r) * q) + ci;
    int t0 = bid * MTOK;
    int tid = threadIdx.x;

    // phase A: softmax -> saw
    if (tid < MTOK * 8) {
        int ti = tid >> 3, h = tid & 7, t = t0 + ti;
        if (t < LEN) {
            const float* lg = offattn + (size_t)t * 384 + 256 + h * 16;
            float w[16], mx = -3.4e38f;
            #pragma unroll
            for (int s = 0; s < 16; ++s) { w[s] = lg[s]; mx = fmaxf(mx, w[s]); }
            float sum = 0.f;
            #pragma unroll
            for (int s = 0; s < 16; ++s) { w[s] = __expf(w[s] - mx); sum += w[s]; }
            float inv = 1.0f / sum;
            #pragma unroll
            for (int s = 0; s < 16; ++s) saw[ti * 128 + h * 16 + s] = w[s] * inv;
        }
    }
    __syncthreads();

    // phase B: fold coords + attention into 4 (weight, byte-offset) per entry
    for (int idx = tid; idx < MTOK * 128; idx += 384) {
        int ti = idx >> 7, rem = idx & 127, h = rem >> 4, p = rem & 15;
        int lvl = p >> 2, pp = p & 3;
        int t = t0 + ti;
        if (t < LEN) {
            float Wl = (float)Wi[lvl], Hl = (float)Hi[lvl];
            const int Wli = Wi[lvl], Hli = Hi[lvl], st = STi[lvl];
            const float* op = offattn + (size_t)t * 384 + h * 32 + lvl * 8 + pp * 2;
            float ox = op[0], oy = op[1];
            float rx = refpts[(size_t)t * 8 + lvl * 2];
            float ry = refpts[(size_t)t * 8 + lvl * 2 + 1];
            float x = rx * Wl + ox - 0.5f;
            float y = ry * Hl + oy - 0.5f;
            float x0f = floorf(x), y0f = floorf(y);
            int x0 = (int)x0f, y0 = (int)y0f;
            float dx = x - x0f, dy = y - y0f;
            float aw = saw[idx];
            float cwv[4] = {(1.f - dx) * (1.f - dy), dx * (1.f - dy),
                            (1.f - dx) * dy, dx * dy};
            #pragma unroll
            for (int c2 = 0; c2 < 4; ++c2) {
                int xi = x0 + (c2 & 1), yi = y0 + (c2 >> 1);
                bool valid = (xi >= 0) & (xi < Wli) & (yi >= 0) & (yi < Hli);
                int xc = min(max(xi, 0), Wli - 1);
                int yc = min(max(yi, 0), Hli - 1);
                si4[idx][c2] = (st + yc * Wli + xc) * 768;   // byte offset
                sw4[idx][c2] = valid ? aw * cwv[c2] : 0.f;
            }
        }
    }
    __syncthreads();

    // phase C: gather. thread = (ti, h, c): 8 contiguous elems of head h.
    int ti = tid / 48;
    int rr = tid - ti * 48;
    int h = rr / 6;
    int c = rr - h * 6;
    int t = t0 + ti;
    if (t >= LEN) return;
    const char* vbc = (const char*)value + (size_t)(h * DHEAD + c * 8) * 2;
    floatx2 a2[4] = {};
    #pragma unroll
    for (int p = 0; p < 16; ++p) {
        int base = ti * 128 + h * 16 + p;
        int4  I = *(const int4*)&si4[base][0];
        float4 W4 = *(const float4*)&sw4[base][0];
        const int   Iv[4] = {I.x, I.y, I.z, I.w};
        const float Wv[4] = {W4.x, W4.y, W4.z, W4.w};
        #pragma unroll
        for (int c2 = 0; c2 < 4; ++c2) {
            shortx8 g = *(const shortx8*)(vbc + Iv[c2]);
            float s = Wv[c2];
            floatx2 s2 = {s, s};
            const unsigned int* gu = (const unsigned int*)&g;
            #pragma unroll
            for (int q2 = 0; q2 < 4; ++q2) {
                unsigned int u = gu[q2];
                floatx2 gf;
                gf[0] = __uint_as_float(u << 16);
                gf[1] = __uint_as_float(u & 0xFFFF0000u);
                a2[q2] += s2 * gf;
            }
        }
    }
    shortx8 o;
    #pragma unroll
    for (int q2 = 0; q2 < 4; ++q2) {
        o[q2 * 2]     = f2bf(a2[q2][0]);
        o[q2 * 2 + 1] = f2bf(a2[q2][1]);
    }
    *(shortx8*)(out + (size_t)t * 384 + h * DHEAD + c * 8) = o;
}

// ---------------------------------------------------------------------------
// MEGA v8 (session-best): MT=32 rows, 557-block grid, 512 threads = 8 waves
// x 48-col strips, barrier-free half-K-step loop, depth-1 register prefetch
// (3 W fragments — depth-2 collapses here, v12), h1 via global f0.
// ---------------------------------------------------------------------------
__global__ __launch_bounds__(512, 2)
void mega_kernel(const ushort* __restrict__ Amsda, const float* __restrict__ src,
                 const ushort* __restrict__ Wo, const ushort* __restrict__ W1,
                 const ushort* __restrict__ W2,
                 const float* __restrict__ bo, const float* __restrict__ b1c,
                 const float* __restrict__ b2c,
                 const float* __restrict__ l1g, const float* __restrict__ l1b,
                 const float* __restrict__ l2g, const float* __restrict__ l2b,
                 float* __restrict__ h1f, float* __restrict__ outp) {
    __shared__ __align__(16) ushort Cbuf[MT * CST];   // 25088 B
    __shared__ __align__(16) floatx4 pst4[MT * 16];   // 8192 B
    __shared__ __align__(16) floatx4 lnf[MT];         // 512 B (total 33792)

    int tid = threadIdx.x;
    int lane = tid & 63, wave = tid >> 6;          // wave 0..7
    int l15 = lane & 15, quad = lane >> 4;
    int wcol = wave * 48;
    int by0 = blockIdx.x * MT;

    floatx4 acc[2][3];

    // ---- stage A (msda output rows) into Cbuf once, coalesced ----
    #pragma unroll
    for (int cix = 0; cix < 3; ++cix) {
        int idx = cix * 512 + tid;          // 0..1535
        int row = idx / 48, c = idx - row * 48;
        int gr = min(by0 + row, LEN - 1);
        *(shortx8*)(Cbuf + row * CST + c * 8) =
            *(const shortx8*)(Amsda + (size_t)gr * 384 + c * 8);
    }
    __syncthreads();

    // ---------------- stage 1: src2 = msda @ Wo^T ----------------
    GEMM384(Wo);
    __syncthreads();                        // all waves done reading Cbuf

    // epilogue 1: x = src2 + b_out + src -> Cbuf (bf16)
    #pragma unroll
    for (int j = 0; j < 3; ++j) {
        int col = wcol + j * 16 + l15;
        float bv = bo[col];
        #pragma unroll
        for (int i = 0; i < 2; ++i)
            #pragma unroll
            for (int rr = 0; rr < 4; ++rr) {
                int row = i * 16 + quad * 4 + rr;
                int gr = min(by0 + row, LEN - 1);
                float x = acc[i][j][rr] + bv + src[(size_t)gr * 384 + col];
                Cbuf[row * CST + col] = f2bf(x);
            }
    }
    __syncthreads();

    // ---- LN1 ---- (512 threads: 16 partials/row, 24 cols each)
    {
        int row = tid >> 4, part = tid & 15;
        float sx = 0.f, qx = 0.f, sz = 0.f, qz = 0.f;
        #pragma unroll
        for (int m = 0; m < 3; ++m) {
            int c0 = part * 24 + m * 8;
            shortx8 v = *(shortx8*)(Cbuf + row * CST + c0);
            float cs = 0.f, cq = 0.f;
            #pragma unroll
            for (int e = 0; e < 8; ++e) { float x = bf2f(v[e]); cs += x; cq += x * x; }
            if (c0 < 256) { sx += cs; qx += cq; } else { sz += cs; qz += cq; }
        }
        pst4[row * 16 + part] = (floatx4){sx, qx, sz, qz};
    }
    __syncthreads();
    if (tid < MT) {
        floatx4 s = (floatx4){0.f, 0.f, 0.f, 0.f};
        #pragma unroll
        for (int p = 0; p < 16; ++p) s += pst4[tid * 16 + p];
        float mx = s[0] / 256.f, vx = s[1] / 256.f - mx * mx;
        float mz = s[2] / 128.f, vz = s[3] / 128.f - mz * mz;
        lnf[tid] = (floatx4){mx, rsqrtf(vx + 1e-5f), mz, rsqrtf(vz + 1e-5f)};
    }
    __syncthreads();
    {
        int row = tid >> 4, part = tid & 15;
        int gr = by0 + row;
        floatx4 L = lnf[row];
        #pragma unroll
        for (int m = 0; m < 3; ++m) {
            int c0 = part * 24 + m * 8;
            bool isxy = c0 < 256;
            float mean = isxy ? L[0] : L[2];
            float inv  = isxy ? L[1] : L[3];
            shortx8 v = *(shortx8*)(Cbuf + row * CST + c0);
            float4 g0 = *(const float4*)(l1g + c0), g1 = *(const float4*)(l1g + c0 + 4);
            float4 e0 = *(const float4*)(l1b + c0), e1 = *(const float4*)(l1b + c0 + 4);
            float gg[8] = {g0.x, g0.y, g0.z, g0.w, g1.x, g1.y, g1.z, g1.w};
            float ee[8] = {e0.x, e0.y, e0.z, e0.w, e1.x, e1.y, e1.z, e1.w};
            float h[8];
            shortx8 hb;
            #pragma unroll
            for (int e = 0; e < 8; ++e) {
                h[e] = (bf2f(v[e]) - mean) * inv * gg[e] + ee[e];
                hb[e] = f2bf(h[e]);
            }
            *(shortx8*)(Cbuf + row * CST + c0) = hb;
            if (gr < LEN) {
                *(float4*)(h1f + (size_t)gr * 384 + c0)     = make_float4(h[0], h[1], h[2], h[3]);
                *(float4*)(h1f + (size_t)gr * 384 + c0 + 4) = make_float4(h[4], h[5], h[6], h[7]);
            }
        }
    }
    __syncthreads();

    // ---------------- stage 2: hidden = relu(h1 @ W1^T + b1) ----------------
    GEMM384(W1);
    __syncthreads();                        // all waves done reading Cbuf
    #pragma unroll
    for (int j = 0; j < 3; ++j) {
        int col = wcol + j * 16 + l15;
        float bv = b1c[col];
        #pragma unroll
        for (int i = 0; i < 2; ++i)
            #pragma unroll
            for (int rr = 0; rr < 4; ++rr) {
                int row = i * 16 + quad * 4 + rr;
                Cbuf[row * CST + col] = f2bf(fmaxf(acc[i][j][rr] + bv, 0.f));
            }
    }
    __syncthreads();

    // ---------------- stage 3: x2 = hidden @ W2^T + b2 + h1 ----------------
    GEMM384(W2);
    __syncthreads();                        // all waves done reading Cbuf
    #pragma unroll
    for (int j = 0; j < 3; ++j) {
        int col = wcol + j * 16 + l15;
        float bv = b2c[col];
        #pragma unroll
        for (int i = 0; i < 2; ++i)
            #pragma unroll
            for (int rr = 0; rr < 4; ++rr) {
                int row = i * 16 + quad * 4 + rr;
                int gr = min(by0 + row, LEN - 1);
                float x = acc[i][j][rr] + bv + h1f[(size_t)gr * 384 + col];
                Cbuf[row * CST + col] = f2bf(x);
            }
    }
    __syncthreads();

    // ---- LN2 -> d_out ----
    {
        int row = tid >> 4, part = tid & 15;
        float sx = 0.f, qx = 0.f, sz = 0.f, qz = 0.f;
        #pragma unroll
        for (int m = 0; m < 3; ++m) {
            int c0 = part * 24 + m * 8;
            shortx8 v = *(shortx8*)(Cbuf + row * CST + c0);
            float cs = 0.f, cq = 0.f;
            #pragma unroll
            for (int e = 0; e < 8; ++e) { float x = bf2f(v[e]); cs += x; cq += x * x; }
            if (c0 < 256) { sx += cs; qx += cq; } else { sz += cs; qz += cq; }
        }
        pst4[row * 16 + part] = (floatx4){sx, qx, sz, qz};
    }
    __syncthreads();
    if (tid < MT) {
        floatx4 s = (floatx4){0.f, 0.f, 0.f, 0.f};
        #pragma unroll
        for (int p = 0; p < 16; ++p) s += pst4[tid * 16 + p];
        float mx = s[0] / 256.f, vx = s[1] / 256.f - mx * mx;
        float mz = s[2] / 128.f, vz = s[3] / 128.f - mz * mz;
        lnf[tid] = (floatx4){mx, rsqrtf(vx + 1e-5f), mz, rsqrtf(vz + 1e-5f)};
    }
    __syncthreads();
    {
        int row = tid >> 4, part = tid & 15;
        int gr = by0 + row;
        if (gr < LEN) {
            floatx4 L = lnf[row];
            #pragma unroll
            for (int m = 0; m < 3; ++m) {
                int c0 = part * 24 + m * 8;
                bool isxy = c0 < 256;
                float mean = isxy ? L[0] : L[2];
                float inv  = isxy ? L[1] : L[3];
                shortx8 v = *(shortx8*)(Cbuf + row * CST + c0);
                float4 g0 = *(const float4*)(l2g + c0), g1 = *(const float4*)(l2g + c0 + 4);
                float4 e0 = *(const float4*)(l2b + c0), e1 = *(const float4*)(l2b + c0 + 4);
                float gg[8] = {g0.x, g0.y, g0.z, g0.w, g1.x, g1.y, g1.z, g1.w};
                float ee[8] = {e0.x, e0.y, e0.z, e0.w, e1.x, e1.y, e1.z, e1.w};
                float h[8];
                #pragma unroll
                for (int e = 0; e < 8; ++e)
                    h[e] = (bf2f(v[e]) - mean) * inv * gg[e] + ee[e];
                *(float4*)(outp + (size_t)gr * 384 + c0)     = make_float4(h[0], h[1], h[2], h[3]);
                *(float4*)(outp + (size_t)gr * 384 + c0 + 4) = make_float4(h[4], h[5], h[6], h[7]);
            }
        }
    }
}

// ---------------------------------------------------------------------------
extern "C" void kernel_launch(void* const* d_in, const int* in_sizes, int n_in,
                              void* d_out, int out_size, void* d_ws, size_t ws_size,
                              hipStream_t stream) {
    const float* src    = (const float*)d_in[0];
    const float* pos    = (const float*)d_in[3];
    const float* refpts = (const float*)d_in[4];
    const float* W_off  = (const float*)d_in[8];
    const float* b_off  = (const float*)d_in[9];
    const float* W_attn = (const float*)d_in[10];
    const float* b_attn = (const float*)d_in[11];
    const float* W_val  = (const float*)d_in[12];
    const float* b_val  = (const float*)d_in[13];
    const float* W_out  = (const float*)d_in[14];
    const float* b_out  = (const float*)d_in[15];
    const float* g1xy = (const float*)d_in[16]; const float* b1xy = (const float*)d_in[17];
    const float* g1zd = (const float*)d_in[18]; const float* b1zd = (const float*)d_in[19];
    const float* fxy_w1 = (const float*)d_in[20]; const float* fxy_b1 = (const float*)d_in[21];
    const float* fxy_w2 = (const float*)d_in[22]; const float* fxy_b2 = (const float*)d_in[23];
    const float* fxy_g  = (const float*)d_in[24]; const float* fxy_b  = (const float*)d_in[25];
    const float* fzd_w1 = (const float*)d_in[26]; const float* fzd_b1 = (const float*)d_in[27];
    const float* fzd_w2 = (const float*)d_in[28]; const float* fzd_b2 = (const float*)d_in[29];
    const float* fzd_g  = (const float*)d_in[30]; const float* fzd_b  = (const float*)d_in[31];

    float* out = (float*)d_out;
    size_t Rn = (size_t)LEN * DMODEL;

    float* f0 = (float*)d_ws;                 // offattn fp32, later h1 fp32
    ushort* sb = (ushort*)(f0 + Rn);
    ushort* s2 = sb + 2 * Rn;                 // value_bf
    ushort* s3 = sb + 3 * Rn;                 // msda_bf
    ushort* wv  = sb + 4 * Rn;
    ushort* woa = wv + WSZ;
    ushort* wo  = woa + WSZ;
    ushort* w1b = wo + WSZ;
    ushort* w2b = w1b + WSZ;
    float* bp = (float*)(w2b + WSZ);
    float* boa = bp;        float* b1c = bp + 384;  float* b2c = bp + 768;
    float* l1g = bp + 1152; float* l1b = bp + 1536;
    float* l2g = bp + 1920; float* l2b = bp + 2304;

    prep_w<<<dim3((WSZ + 255) / 256, 5), 256, 0, stream>>>(
        W_val, W_off, W_attn, W_out, fxy_w1, fzd_w1, fxy_w2, fzd_w2,
        wv, woa, wo, w1b, w2b);
    prep_b<<<1, 384, 0, stream>>>(b_off, b_attn, fxy_b1, fzd_b1, fxy_b2, fzd_b2,
                                  g1xy, b1xy, g1zd, b1zd, fxy_g, fxy_b, fzd_g, fzd_b,
                                  boa, b1c, b2c, l1g, l1b, l2g, l2b);

    vq_gemm<<<dim3((LEN + MT - 1) / MT, 2), 512, 0, stream>>>(
        src, pos, wv, woa, b_val, boa, s2, f0);

    int nwg = (LEN + MTOK - 1) / MTOK;
    msda_v5<<<nwg, 384, 0, stream>>>(s2, f0, refpts, s3, nwg);

    mega_kernel<<<(LEN + MT - 1) / MT, 512, 0, stream>>>(
        s3, src, wo, w1b, w2b, b_out, b1c, b2c,
        l1g, l1b, l2g, l2b, f0, out);
}